// Round 6
// baseline (277.591 us; speedup 1.0000x reference)
//
#include <hip/hip_runtime.h>
#include <stdint.h>
#include <stddef.h>

typedef unsigned short u16;
typedef __bf16 bf16t;
typedef bf16t bf16x8 __attribute__((ext_vector_type(8)));
typedef u16 u16x8 __attribute__((ext_vector_type(8)));
typedef u16 u16x4 __attribute__((ext_vector_type(4)));
typedef float f32x4 __attribute__((ext_vector_type(4)));

// ---------- helpers ----------
__device__ __forceinline__ float bf2f(u16 u) {
  unsigned int x = ((unsigned int)u) << 16;
  return __builtin_bit_cast(float, x);
}
__device__ __forceinline__ u16 f2bf(float f) {
  unsigned int x = __builtin_bit_cast(unsigned int, f);
  x += 0x7fffu + ((x >> 16) & 1u);
  return (u16)(x >> 16);
}
__device__ __forceinline__ u16x8 ld8(const u16* p) { return *(const u16x8*)p; }

__device__ __forceinline__ f32x4 mfma_bf16(u16x8 a, u16x8 b, f32x4 c) {
  return __builtin_amdgcn_mfma_f32_16x16x32_bf16(
      __builtin_bit_cast(bf16x8, a), __builtin_bit_cast(bf16x8, b), c, 0, 0, 0);
}
__device__ __forceinline__ void g2lds16(const u16* g, u16* l) {
  __builtin_amdgcn_global_load_lds(
      (const __attribute__((address_space(1))) unsigned int*)g,
      (__attribute__((address_space(3))) unsigned int*)l, 16, 0, 0);
}
__device__ __forceinline__ void stc(u16* p, float v) { *p = f2bf(v); }
__device__ __forceinline__ void stc(float* p, float v) { *p = v; }

// erf via Abramowitz–Stegun 7.1.26 (|err|<=1.5e-7), one __expf
__device__ __forceinline__ float fast_erf(float x) {
  const float ax = fabsf(x);
  const float t = 1.0f / (1.0f + 0.3275911f * ax);
  const float y = 1.0f - (((((1.061405429f * t - 1.453152027f) * t) + 1.421413741f) * t
                  - 0.284496736f) * t + 0.254829592f) * t * __expf(-ax * ax);
  return copysignf(y, x);
}

// ---------- constants ----------
// B=8 K=1024 D=256 H=8 hd=32 R=4 L=1028 Ltok=8224 Mpad=8320 (65*128)
// qkv fused: [8320][1536] = [q_c k_c v_c | q_t k_t v_t]

// ---------- kernel 0: convert f32 weights -> bf16 + concat QKV bias ----------
__global__ __launch_bounds__(256) void cvt_kernel(
    const float* __restrict__ s0, const float* __restrict__ s1,
    const float* __restrict__ s2, const float* __restrict__ s3,
    const float* __restrict__ s4, const float* __restrict__ s5,
    u16* __restrict__ d0, u16* __restrict__ d1, u16* __restrict__ d2,
    u16* __restrict__ d3, u16* __restrict__ d4, u16* __restrict__ d5,
    const float* __restrict__ cb, const float* __restrict__ tb,
    float* __restrict__ biasq)
{
  const int blk = blockIdx.x;
  if (blk >= 1024) {                       // QKV bias concat (f32)
    const int e0 = (blk - 1024) * 1024 + threadIdx.x * 4;
    #pragma unroll
    for (int j = 0; j < 4; ++j) {
      const int e = e0 + j;
      if (e < 1536) biasq[e] = e < 768 ? cb[e] : tb[e - 768];
    }
    return;
  }
  const float* s; u16* d; int lb;
  if (blk < 192)      { s = s0; d = d0; lb = blk; }
  else if (blk < 384) { s = s1; d = d1; lb = blk - 192; }
  else if (blk < 448) { s = s2; d = d2; lb = blk - 384; }
  else if (blk < 512) { s = s3; d = d3; lb = blk - 448; }
  else if (blk < 768) { s = s4; d = d4; lb = blk - 512; }
  else                { s = s5; d = d5; lb = blk - 768; }
  const size_t e = ((size_t)lb * 256 + threadIdx.x) * 4;
  const f32x4 v = *(const f32x4*)(s + e);
  u16x4 o;
  #pragma unroll
  for (int j = 0; j < 4; ++j) o[j] = f2bf(v[j]);
  *(u16x4*)(d + e) = o;
}

// ---------- kernel 1: embed + rope2d + registers + LN (wave-per-row) ----------
__global__ __launch_bounds__(256) void prep_kernel(
    const float* __restrict__ x, const int* __restrict__ coords,
    const int* __restrict__ labels, const float* __restrict__ tgt_e,
    const float* __restrict__ ctx_e, const float* __restrict__ regs,
    const float* __restrict__ rope, const float* __restrict__ g,
    const float* __restrict__ bt, float* __restrict__ x0,
    u16* __restrict__ xn)
{
  const int wv = threadIdx.x >> 6, lane = threadIdx.x & 63;
  const int t = blockIdx.x * 4 + wv;   // 0..8319
  const int d = lane * 4;
  if (t >= 8224) {                     // pad rows: defined zeros (QKV A-tiles)
    *(u16x4*)&xn[(size_t)t * 256 + d] = (u16x4){0, 0, 0, 0};
    return;
  }
  const int b = t / 1028, l = t - b * 1028;
  f32x4 v;
  if (l < 4) {
    const f32x4 rg = *(const f32x4*)&regs[l * 256 + d];
    const f32x4 ce = *(const f32x4*)&ctx_e[d];
    #pragma unroll
    for (int j = 0; j < 4; ++j) v[j] = rg[j] + ce[j];
  } else {
    const int p = l - 4;
    const bool ic = labels[b * 1024 + p] > 0;
    const float* emb = ic ? ctx_e : tgt_e;
    const int cy = coords[(b * 1024 + p) * 2 + 0];
    const int cx = coords[(b * 1024 + p) * 2 + 1];
    const float fy = fminf(fmaxf(((float)cy / 224.0f) * 1023.0f, 0.0f), 1023.0f);
    const float fx = fminf(fmaxf(((float)cx / 224.0f) * 1023.0f, 0.0f), 1023.0f);
    const int yi = (int)fy, xi = (int)fx;
    const bool second = d >= 128;
    const int ci = second ? yi : xi;
    const int pairi = (d & 127) >> 1;
    const f32x4 rr = *(const f32x4*)&rope[ci * 128 + pairi * 2];  // cA sA cB sB
    const int i0 = (second ? 128 : 0) + pairi * 2;
    const size_t base = (size_t)(b * 1024 + p) * 256;
    const f32x4 xv = *(const f32x4*)&x[base + i0];
    const f32x4 ev = *(const f32x4*)&emb[i0];
    const float p0 = xv[0] + ev[0], p1 = xv[1] + ev[1];
    const float p2 = xv[2] + ev[2], p3 = xv[3] + ev[3];
    v[0] = p0 * rr[0] - p1 * rr[1];
    v[1] = p0 * rr[1] + p1 * rr[0];
    v[2] = p2 * rr[2] - p3 * rr[3];
    v[3] = p2 * rr[3] + p3 * rr[2];
  }
  *(f32x4*)&x0[(size_t)t * 256 + d] = v;
  float s1 = v[0] + v[1] + v[2] + v[3];
  #pragma unroll
  for (int off = 1; off < 64; off <<= 1) s1 += __shfl_xor(s1, off);
  const float mean = s1 * (1.0f / 256.0f);
  f32x4 dv;
  float s2 = 0.f;
  #pragma unroll
  for (int j = 0; j < 4; ++j) { dv[j] = v[j] - mean; s2 += dv[j] * dv[j]; }
  #pragma unroll
  for (int off = 1; off < 64; off <<= 1) s2 += __shfl_xor(s2, off);
  const float rstd = rsqrtf(s2 * (1.0f / 256.0f) + 1e-5f);
  const f32x4 gv = *(const f32x4*)&g[d];
  const f32x4 bv = *(const f32x4*)&bt[d];
  u16x4 o;
  #pragma unroll
  for (int j = 0; j < 4; ++j) o[j] = f2bf(dv[j] * rstd * gv[j] + bv[j]);
  *(u16x4*)&xn[(size_t)t * 256 + d] = o;
}

// ---------- kernel 2: per-batch compaction (keys + per-branch queries) ----------
__global__ __launch_bounds__(1024) void compact_kernel(
    const int* __restrict__ labels, int* __restrict__ qidx_c,
    int* __restrict__ qidx_t, int* __restrict__ qcnt_c,
    int* __restrict__ qcnt_t, int* __restrict__ kidx,
    float* __restrict__ keyb, int* __restrict__ nktb,
    int* __restrict__ slotm)
{
  const int b = blockIdx.x, tid = threadIdx.x;
  const int wave = tid >> 6, lane = tid & 63;
  const bool ic = labels[b * 1024 + tid] > 0;
  const unsigned long long mask = __ballot(ic);
  const int lower = __popcll(mask & ((1ull << lane) - 1ull));
  const int wc = __popcll(mask);
  __shared__ int wcnt[16], woff[17];
  if (lane == 0) wcnt[wave] = wc;
  kidx[b * 1088 + tid] = b * 1028;       // pad defaults (register row 0)
  keyb[b * 1088 + tid] = -1e30f;
  if (tid < 64) { kidx[b * 1088 + 1024 + tid] = b * 1028;
                  keyb[b * 1088 + 1024 + tid] = -1e30f; }
  __syncthreads();
  if (tid == 0) {
    int acc = 0;
    #pragma unroll
    for (int i = 0; i < 16; ++i) { woff[i] = acc; acc += wcnt[i]; }
    woff[16] = acc;
  }
  __syncthreads();
  const int nc = woff[16];
  const int nt = 1024 - nc;
  const int rank_c = woff[wave] + lower;
  const int rank_t = tid - woff[wave] - lower;
  const int grow = b * 1028 + 4 + tid;
  if (ic) {
    qidx_c[b * 1024 + rank_c] = grow;
    slotm[b * 1024 + tid] = rank_c;
    kidx[b * 1088 + 4 + rank_c] = grow;
    keyb[b * 1088 + 4 + rank_c] = 0.0f;
  } else {
    qidx_t[b * 1024 + rank_t] = grow;
    slotm[b * 1024 + tid] = rank_t;
  }
  if (tid < 4) { kidx[b * 1088 + tid] = b * 1028 + tid;
                 keyb[b * 1088 + tid] = 0.0f; }
  const int ncp = (nc + 63) & ~63;
  const int ntp = (nt + 63) & ~63;
  if (tid >= nc && tid < ncp) qidx_c[b * 1024 + tid] = b * 1028;
  if (tid >= nt && tid < ntp) qidx_t[b * 1024 + tid] = b * 1028;
  if (tid == 0) {
    qcnt_c[b] = nc; qcnt_t[b] = nt;
    nktb[b] = (nc + 4 + 63) >> 6;
  }
}

// ---------- generic GEMM: C[M,N] = A[M,K] @ W[N,K]^T + bias ----------
template <int EPI, typename CT>
__global__ __launch_bounds__(256) void gemm_bt(
    const u16* __restrict__ A, int lda, const u16* __restrict__ W, int K,
    const float* __restrict__ bias, CT* __restrict__ C, int ldc, int M,
    const float* __restrict__ resid)
{
  const int mbase = blockIdx.y * 128, nbase = blockIdx.x * 128;
  __shared__ u16 As[128 * 32];
  __shared__ u16 Bs[128 * 32];
  const int tid = threadIdx.x, lane = tid & 63, w = tid >> 6;
  const int quad = lane >> 4, r = lane & 15;
  const int wm = w >> 1, wn = w & 1;
  const int rA = lane >> 2, cA = (lane & 3) * 8;

  f32x4 acc[4][4];
  #pragma unroll
  for (int i = 0; i < 4; ++i)
    #pragma unroll
    for (int j = 0; j < 4; ++j) acc[i][j] = (f32x4){0.f, 0.f, 0.f, 0.f};

  const int nkt = K >> 5;
  for (int kt = 0; kt < nkt; ++kt) {
    const int k0 = kt * 32;
    #pragma unroll
    for (int j = 0; j < 2; ++j) {
      const int rr = w * 32 + j * 16;
      g2lds16(&A[(size_t)(mbase + rr + rA) * lda + k0 + cA], &As[rr * 32]);
      g2lds16(&W[(size_t)(nbase + rr + rA) * K + k0 + cA], &Bs[rr * 32]);
    }
    __syncthreads();
    u16x8 av[4], bv[4];
    #pragma unroll
    for (int mi = 0; mi < 4; ++mi) av[mi] = ld8(&As[(wm * 64 + mi * 16 + r) * 32 + quad * 8]);
    #pragma unroll
    for (int ni = 0; ni < 4; ++ni) bv[ni] = ld8(&Bs[(wn * 64 + ni * 16 + r) * 32 + quad * 8]);
    #pragma unroll
    for (int mi = 0; mi < 4; ++mi)
      #pragma unroll
      for (int ni = 0; ni < 4; ++ni)
        acc[mi][ni] = mfma_bf16(av[mi], bv[ni], acc[mi][ni]);
    __syncthreads();
  }

  #pragma unroll
  for (int mi = 0; mi < 4; ++mi) {
    #pragma unroll
    for (int ni = 0; ni < 4; ++ni) {
      const int col = nbase + wn * 64 + ni * 16 + r;
      const float bs = bias[col];
      const int row0 = mbase + wm * 64 + mi * 16 + quad * 4;
      #pragma unroll
      for (int i = 0; i < 4; ++i) {
        const int rr2 = row0 + i;
        if (rr2 < M) {
          float v = acc[mi][ni][i] + bs;
          if (EPI == 1) v = 0.5f * v * (1.0f + fast_erf(v * 0.70710678118654752f));
          if (EPI == 2) v += resid[(size_t)rr2 * ldc + col];
          stc(&C[(size_t)rr2 * ldc + col], v);
        }
      }
    }
  }
}

// ---------- Wo GEMM, both branches in one dispatch (z = branch) ----------
__global__ __launch_bounds__(256) void gemm_wo(
    const u16* __restrict__ Ac, const u16* __restrict__ At,
    const u16* __restrict__ Wc, const u16* __restrict__ Wt,
    const float* __restrict__ bc, const float* __restrict__ btg,
    u16* __restrict__ Cc, u16* __restrict__ Ct,
    const int* __restrict__ cnt_c, const int* __restrict__ cnt_t)
{
  const int z = blockIdx.z;
  const int mbase = blockIdx.y * 128, nbase = blockIdx.x * 128;
  const int* bcnt = z ? cnt_t : cnt_c;
  const int bb = mbase >> 10;
  const int need = (bcnt[bb] + 127) & ~127;
  if ((mbase & 1023) >= need) return;
  const u16* A = z ? At : Ac;
  const u16* W = z ? Wt : Wc;
  const float* bias = z ? btg : bc;
  u16* C = z ? Ct : Cc;

  __shared__ u16 As[128 * 32];
  __shared__ u16 Bs[128 * 32];
  const int tid = threadIdx.x, lane = tid & 63, w = tid >> 6;
  const int quad = lane >> 4, r = lane & 15;
  const int wm = w >> 1, wn = w & 1;
  const int rA = lane >> 2, cA = (lane & 3) * 8;

  f32x4 acc[4][4];
  #pragma unroll
  for (int i = 0; i < 4; ++i)
    #pragma unroll
    for (int j = 0; j < 4; ++j) acc[i][j] = (f32x4){0.f, 0.f, 0.f, 0.f};

  for (int kt = 0; kt < 8; ++kt) {
    const int k0 = kt * 32;
    #pragma unroll
    for (int j = 0; j < 2; ++j) {
      const int rr = w * 32 + j * 16;
      g2lds16(&A[(size_t)(mbase + rr + rA) * 256 + k0 + cA], &As[rr * 32]);
      g2lds16(&W[(size_t)(nbase + rr + rA) * 256 + k0 + cA], &Bs[rr * 32]);
    }
    __syncthreads();
    u16x8 av[4], bv[4];
    #pragma unroll
    for (int mi = 0; mi < 4; ++mi) av[mi] = ld8(&As[(wm * 64 + mi * 16 + r) * 32 + quad * 8]);
    #pragma unroll
    for (int ni = 0; ni < 4; ++ni) bv[ni] = ld8(&Bs[(wn * 64 + ni * 16 + r) * 32 + quad * 8]);
    #pragma unroll
    for (int mi = 0; mi < 4; ++mi)
      #pragma unroll
      for (int ni = 0; ni < 4; ++ni)
        acc[mi][ni] = mfma_bf16(av[mi], bv[ni], acc[mi][ni]);
    __syncthreads();
  }

  #pragma unroll
  for (int mi = 0; mi < 4; ++mi) {
    #pragma unroll
    for (int ni = 0; ni < 4; ++ni) {
      const int col = nbase + wn * 64 + ni * 16 + r;
      const float bs = bias[col];
      const int row0 = mbase + wm * 64 + mi * 16 + quad * 4;
      #pragma unroll
      for (int i = 0; i < 4; ++i) {
        const int rr2 = row0 + i;
        C[(size_t)rr2 * 256 + col] = f2bf(acc[mi][ni][i] + bs);
      }
    }
  }
}

// ---------- kernel 3: compacted flash attention, both branches, pipelined ----------
// Double-buffered K/V gather: DMA for tile t+1 issued right after barrier(t),
// drained by barrier(t+1) after a full compute phase. One barrier per tile.
__global__ __launch_bounds__(256) void attn3_kernel(
    const u16* __restrict__ qkv, const float* __restrict__ bq_c,
    const float* __restrict__ bq_t, const int* __restrict__ qidx_c,
    const int* __restrict__ qidx_t, const int* __restrict__ qcnt_c,
    const int* __restrict__ qcnt_t, const int* __restrict__ kidx,
    const float* __restrict__ keyb, const int* __restrict__ nktb,
    u16* __restrict__ o_c, u16* __restrict__ o_t)
{
  const int qb = blockIdx.x, h = blockIdx.y, z = blockIdx.z;
  const int b = qb >> 4, qb_in = qb & 15;
  const int* qcnt = z ? qcnt_t : qcnt_c;
  if (qb_in * 64 >= qcnt[b]) return;
  const float* bqkv = z ? bq_t : bq_c;
  const int* qidx = z ? qidx_t : qidx_c;
  u16* obuf = z ? o_t : o_c;
  const u16* qz = qkv + z * 768;

  const int tid = threadIdx.x, lane = tid & 63, w = tid >> 6;
  const int quad = lane >> 4, r = lane & 15;
  const float scale = 0.17677669529663687f;  // 1/sqrt(32)

  __shared__ u16 Ks[2][64 * 32];     // [key][dim] double-buffered
  __shared__ u16 Vt[2][32 * 66];     // [dim][key] stride 66, double-buffered
  __shared__ u16 Ps[4][16 * 72];     // per-wave P [q][key] stride 72
  __shared__ int kidxS[1088];
  __shared__ float keybS[1088];

  for (int i = tid; i < 1088; i += 256) {
    kidxS[i] = kidx[b * 1088 + i];
    keybS[i] = keyb[b * 1088 + i];
  }

  const int qslot = qb_in * 64 + w * 16 + r;
  const int qrow = qidx[b * 1024 + qslot];
  const u16x8 qf = ld8(&qz[(size_t)qrow * 1536 + h * 32 + quad * 8]);

  float s0 = 0.f;
  #pragma unroll
  for (int j = 0; j < 8; ++j) s0 += bf2f(qf[j]) * bqkv[256 + h * 32 + quad * 8 + j];
  s0 *= scale;
  s0 += __shfl_xor(s0, 16);
  s0 += __shfl_xor(s0, 32);
  float m_ = s0, l_ = 1.0f;
  f32x4 accA, accB;
  #pragma unroll
  for (int i = 0; i < 4; ++i) {
    accA[i] = bqkv[512 + h * 32 + quad * 4 + i];
    accB[i] = bqkv[512 + h * 32 + 16 + quad * 4 + i];
  }

  const int key = tid >> 2, dc = (tid & 3) * 8;
  const int ntile = nktb[b];
  __syncthreads();                     // kidxS/keybS ready

  // preload tile 0
  {
    const int krow = kidxS[key];
    g2lds16(&qz[(size_t)krow * 1536 + 256 + h * 32 + dc], &Ks[0][w * 512]);
  }
  u16x8 vv = ld8(&qz[(size_t)kidxS[key] * 1536 + 512 + h * 32 + dc]);

  for (int t = 0; t < ntile; ++t) {
    const int cur = t & 1, nxt = cur ^ 1;
    // scatter this tile's V (register) into Vt[cur] — readers sync below
    #pragma unroll
    for (int j = 0; j < 8; ++j) Vt[cur][(dc + j) * 66 + key] = vv[j];
    __syncthreads();                   // drains DMA(t) (issued last iter) + V scatters
    if (t + 1 < ntile) {               // prefetch tile t+1 (drained at NEXT barrier)
      const int krow2 = kidxS[(t + 1) * 64 + key];
      g2lds16(&qz[(size_t)krow2 * 1536 + 256 + h * 32 + dc], &Ks[nxt][w * 512]);
      vv = ld8(&qz[(size_t)krow2 * 1536 + 512 + h * 32 + dc]);
    }

    f32x4 sT[4];
    #pragma unroll
    for (int tt = 0; tt < 4; ++tt) {
      const u16x8 kf = ld8(&Ks[cur][(tt * 16 + r) * 32 + quad * 8]);
      sT[tt] = mfma_bf16(kf, qf, (f32x4){0.f, 0.f, 0.f, 0.f});
    }
    float rm = -3.0e38f;
    float sc[4][4];
    #pragma unroll
    for (int tt = 0; tt < 4; ++tt)
      #pragma unroll
      for (int i = 0; i < 4; ++i) {
        sc[tt][i] = sT[tt][i] * scale + keybS[t * 64 + tt * 16 + quad * 4 + i];
        rm = fmaxf(rm, sc[tt][i]);
      }
    rm = fmaxf(rm, __shfl_xor(rm, 16));
    rm = fmaxf(rm, __shfl_xor(rm, 32));
    const float mn = fmaxf(m_, rm);
    const float al = __expf(m_ - mn);
    m_ = mn;
    float rs = 0.f;
    u16* ps = &Ps[w][r * 72];
    #pragma unroll
    for (int tt = 0; tt < 4; ++tt) {
      u16x4 pk;
      #pragma unroll
      for (int i = 0; i < 4; ++i) {
        const float pv = __expf(sc[tt][i] - mn);
        rs += pv;
        pk[i] = f2bf(pv);
      }
      *(u16x4*)&ps[tt * 16 + quad * 4] = pk;
    }
    rs += __shfl_xor(rs, 16);
    rs += __shfl_xor(rs, 32);
    l_ = l_ * al + rs;
    #pragma unroll
    for (int i = 0; i < 4; ++i) { accA[i] *= al; accB[i] *= al; }
    #pragma unroll
    for (int kk = 0; kk < 2; ++kk) {
      const u16x8 pf = ld8(&Ps[w][r * 72 + kk * 32 + quad * 8]);
      const u16x8 vf0 = ld8(&Vt[cur][r * 66 + kk * 32 + quad * 8]);
      const u16x8 vf1 = ld8(&Vt[cur][(16 + r) * 66 + kk * 32 + quad * 8]);
      accA = mfma_bf16(vf0, pf, accA);
      accB = mfma_bf16(vf1, pf, accB);
    }
  }

  const float inv = 1.0f / l_;
  u16x4 oa, ob;
  #pragma unroll
  for (int i = 0; i < 4; ++i) { oa[i] = f2bf(accA[i] * inv); ob[i] = f2bf(accB[i] * inv); }
  const size_t orow = (size_t)b * 1024 + qslot;
  *(u16x4*)&obuf[orow * 256 + h * 32 + quad * 4] = oa;
  *(u16x4*)&obuf[orow * 256 + h * 32 + 16 + quad * 4] = ob;
}

// ---------- kernel 4: branch select + residual + LN (wave-per-row) ----------
__global__ __launch_bounds__(256) void select_ln_kernel(
    const float* __restrict__ x0, const u16* __restrict__ po_c,
    const u16* __restrict__ po_t, const int* __restrict__ labels,
    const int* __restrict__ slotm, const float* __restrict__ g,
    const float* __restrict__ bt, float* __restrict__ x1,
    u16* __restrict__ hln)
{
  const int wv = threadIdx.x >> 6, lane = threadIdx.x & 63;
  const int t = blockIdx.x * 4 + wv;          // 0..8191
  const int d = lane * 4;
  const int b = t >> 10;
  const size_t row = (size_t)b * 1028 + 4 + (t & 1023);
  const bool ic = labels[t] > 0;
  const u16* po = ic ? po_c : po_t;
  const int slot = slotm[t];
  const f32x4 xv = *(const f32x4*)&x0[row * 256 + d];
  const u16x4 pv = *(const u16x4*)&po[((size_t)b * 1024 + slot) * 256 + d];
  f32x4 v;
  #pragma unroll
  for (int j = 0; j < 4; ++j) v[j] = xv[j] + bf2f(pv[j]);
  *(f32x4*)&x1[(size_t)t * 256 + d] = v;
  float s1 = v[0] + v[1] + v[2] + v[3];
  #pragma unroll
  for (int off = 1; off < 64; off <<= 1) s1 += __shfl_xor(s1, off);
  const float mean = s1 * (1.0f / 256.0f);
  f32x4 dv;
  float s2 = 0.f;
  #pragma unroll
  for (int j = 0; j < 4; ++j) { dv[j] = v[j] - mean; s2 += dv[j] * dv[j]; }
  #pragma unroll
  for (int off = 1; off < 64; off <<= 1) s2 += __shfl_xor(s2, off);
  const float rstd = rsqrtf(s2 * (1.0f / 256.0f) + 1e-5f);
  const f32x4 gv = *(const f32x4*)&g[d];
  const f32x4 bv = *(const f32x4*)&bt[d];
  u16x4 o;
  #pragma unroll
  for (int j = 0; j < 4; ++j) o[j] = f2bf(dv[j] * rstd * gv[j] + bv[j]);
  *(u16x4*)&hln[(size_t)t * 256 + d] = o;
}

// ---------- launch ----------
extern "C" void kernel_launch(void* const* d_in, const int* in_sizes, int n_in,
                              void* d_out, int out_size, void* d_ws, size_t ws_size,
                              hipStream_t stream) {
  const float* x      = (const float*)d_in[0];
  const int*   coords = (const int*)d_in[1];
  const int*   labels = (const int*)d_in[2];
  const float* tgt_e  = (const float*)d_in[3];
  const float* ctx_e  = (const float*)d_in[4];
  const float* regs   = (const float*)d_in[5];
  const float* rope   = (const float*)d_in[6];
  const float* ng     = (const float*)d_in[7];
  const float* nb     = (const float*)d_in[8];
  const float* cWqkv  = (const float*)d_in[9];
  const float* cbqkv  = (const float*)d_in[10];
  const float* cWo    = (const float*)d_in[11];
  const float* cbo    = (const float*)d_in[12];
  const float* tWqkv  = (const float*)d_in[13];
  const float* tbqkv  = (const float*)d_in[14];
  const float* tWo    = (const float*)d_in[15];
  const float* tbo    = (const float*)d_in[16];
  const float* mg     = (const float*)d_in[17];
  const float* mbeta  = (const float*)d_in[18];
  const float* W1     = (const float*)d_in[19];
  const float* b1     = (const float*)d_in[20];
  const float* W2     = (const float*)d_in[21];
  const float* b2     = (const float*)d_in[22];

  char* ws = (char*)d_ws;
  float* x0     = (float*)(ws + 0);            // 8224x256 f32
  u16*   xn     = (u16*)  (ws + 8421376);      // 8320x256 bf16
  u16*   wq_ct  = (u16*)  (ws + 12681216);     // 1536x256 bf16
  float* biasq  = (float*)(ws + 13467648);     // 1536 f32
  u16*   woc    = (u16*)  (ws + 13473792);     // 256x256
  u16*   wot    = (u16*)  (ws + 13604864);
  u16*   w1b    = (u16*)  (ws + 13735936);     // 1024x256
  u16*   w2b    = (u16*)  (ws + 14260224);     // 256x1024 -> 14,784,512
  u16*   qkv    = (u16*)  (ws + 14784512);     // 8320x1536 -> 40,343,552
  u16*   o_c    = (u16*)  (ws + 40343552);     // 8192x256 -> 44,537,856
  u16*   o_t    = (u16*)  (ws + 44537856);     //          -> 48,732,160
  float* x1     = (float*)(ws + 48732160);     // 8192x256 f32 -> 57,120,768
  u16*   hln    = (u16*)  (ws + 57120768);     // 8192x256 -> 61,315,072
  int*   qidx_c = (int*)  (ws + 61315072);     // 8192 int
  int*   qidx_t = (int*)  (ws + 61347840);
  int*   kidx   = (int*)  (ws + 61380608);     // 8x1088
  float* keyb   = (float*)(ws + 61415424);     // 8x1088
  int*   slotm  = (int*)  (ws + 61450240);     // 8192
  int*   qcnt_c = (int*)  (ws + 61483008);     // 8
  int*   qcnt_t = (int*)  (ws + 61483040);     // 8
  int*   nktb   = (int*)  (ws + 61483072);     // 8
  // aliases into dead qkv region (qkv consumed by attn before these writes):
  u16*   po_c   = (u16*)  (ws + 14784512);     // 8192x256
  u16*   po_t   = (u16*)  (ws + 18978816);
  u16*   hmid   = (u16*)  (ws + 23173120);     // 8192x1024 -> 39,950,336

  cvt_kernel<<<dim3(1026), 256, 0, stream>>>(
      cWqkv, tWqkv, cWo, tWo, W1, W2,
      wq_ct, wq_ct + 768 * 256, woc, wot, w1b, w2b, cbqkv, tbqkv, biasq);
  prep_kernel<<<dim3(2080), 256, 0, stream>>>(x, coords, labels, tgt_e, ctx_e,
                                              regs, rope, ng, nb, x0, xn);
  compact_kernel<<<dim3(8), 1024, 0, stream>>>(labels, qidx_c, qidx_t, qcnt_c,
                                               qcnt_t, kidx, keyb, nktb, slotm);
  gemm_bt<0, u16><<<dim3(12, 65), 256, 0, stream>>>(xn, 256, wq_ct, 256, biasq, qkv, 1536, 8320, nullptr);
  attn3_kernel<<<dim3(128, 8, 2), 256, 0, stream>>>(qkv, cbqkv, tbqkv, qidx_c, qidx_t,
                                                    qcnt_c, qcnt_t, kidx, keyb, nktb, o_c, o_t);
  gemm_wo<<<dim3(2, 64, 2), 256, 0, stream>>>(o_c, o_t, woc, wot, cbo, tbo, po_c, po_t, qcnt_c, qcnt_t);
  select_ln_kernel<<<dim3(2048), 256, 0, stream>>>(x0, po_c, po_t, labels, slotm, mg, mbeta, x1, hln);
  gemm_bt<1, u16><<<dim3(8, 64), 256, 0, stream>>>(hln, 256, w1b, 256, b1, hmid, 1024, 8192, nullptr);
  gemm_bt<2, float><<<dim3(2, 64), 256, 0, stream>>>(hmid, 1024, w2b, 1024, b2, (float*)d_out, 256, 8192, x1);
}

// Round 7
// 250.172 us; speedup vs baseline: 1.1096x; 1.1096x over previous
//
#include <hip/hip_runtime.h>
#include <stdint.h>
#include <stddef.h>

typedef unsigned short u16;
typedef __bf16 bf16t;
typedef bf16t bf16x8 __attribute__((ext_vector_type(8)));
typedef u16 u16x8 __attribute__((ext_vector_type(8)));
typedef u16 u16x4 __attribute__((ext_vector_type(4)));
typedef float f32x4 __attribute__((ext_vector_type(4)));

// ---------- helpers ----------
__device__ __forceinline__ float bf2f(u16 u) {
  unsigned int x = ((unsigned int)u) << 16;
  return __builtin_bit_cast(float, x);
}
__device__ __forceinline__ u16 f2bf(float f) {
  unsigned int x = __builtin_bit_cast(unsigned int, f);
  x += 0x7fffu + ((x >> 16) & 1u);
  return (u16)(x >> 16);
}
__device__ __forceinline__ u16x8 ld8(const u16* p) { return *(const u16x8*)p; }

__device__ __forceinline__ f32x4 mfma_bf16(u16x8 a, u16x8 b, f32x4 c) {
  return __builtin_amdgcn_mfma_f32_16x16x32_bf16(
      __builtin_bit_cast(bf16x8, a), __builtin_bit_cast(bf16x8, b), c, 0, 0, 0);
}
__device__ __forceinline__ void g2lds16(const u16* g, u16* l) {
  __builtin_amdgcn_global_load_lds(
      (const __attribute__((address_space(1))) unsigned int*)g,
      (__attribute__((address_space(3))) unsigned int*)l, 16, 0, 0);
}
__device__ __forceinline__ void stc(u16* p, float v) { *p = f2bf(v); }
__device__ __forceinline__ void stc(float* p, float v) { *p = v; }

// erf via Abramowitz–Stegun 7.1.26 (|err|<=1.5e-7), one __expf
__device__ __forceinline__ float fast_erf(float x) {
  const float ax = fabsf(x);
  const float t = 1.0f / (1.0f + 0.3275911f * ax);
  const float y = 1.0f - (((((1.061405429f * t - 1.453152027f) * t) + 1.421413741f) * t
                  - 0.284496736f) * t + 0.254829592f) * t * __expf(-ax * ax);
  return copysignf(y, x);
}

// ---------- constants ----------
// B=8 K=1024 D=256 H=8 hd=32 R=4 L=1028 Ltok=8224
// Compacted: xnc [8][1152][256] (rows 0-3 regs, 4..nc+3 ctx tokens, pad 0),
//            xnt [8][1024][256] (tgt tokens, pad 0).
// ctx GEMM N=1280 = [q_c k_c v_c k_t v_t]; K/V scattered to dense per-head:
//   kbuf[z][b][h][slot<1152][32], vbufT[z][b][h][d<32][slot<1152]  (36864 u16 per zbh)

// ---------- kernel 0: weights->bf16 with QKV re-layout + biases ----------
__global__ __launch_bounds__(256) void cvt_kernel(
    const float* __restrict__ cW, const float* __restrict__ tW,
    const float* __restrict__ cWo_, const float* __restrict__ tWo_,
    const float* __restrict__ W1_, const float* __restrict__ W2_,
    const float* __restrict__ cb, const float* __restrict__ tb,
    u16* __restrict__ wA, u16* __restrict__ wB, u16* __restrict__ woc,
    u16* __restrict__ wot, u16* __restrict__ w1b, u16* __restrict__ w2b,
    float* __restrict__ bA, float* __restrict__ bB)
{
  const int blk = blockIdx.x;
  if (blk >= 1024) {                         // bias assembly (f32)
    const int e = threadIdx.x * 4;
    if (blk == 1024) {
      #pragma unroll
      for (int j = 0; j < 4; ++j) {
        const int k = e + j;
        bA[k] = (k < 768) ? cb[k] : tb[k - 512];   // [cb_q cb_k cb_v tb_k]
      }
    } else {
      #pragma unroll
      for (int j = 0; j < 4; ++j) {
        const int k = e + j;
        if (k < 256) bA[1024 + k] = tb[512 + k];   // tb_v
        else if (k < 512) bB[k - 256] = tb[k - 256]; // tb_q
      }
    }
    return;
  }
  const float* s; u16* d;
  if (blk < 192)      { const size_t e = (size_t)blk * 1024; s = cW + e; d = wA + e; }
  else if (blk < 384) { const int lb = blk - 192; const size_t e = (size_t)lb * 1024;
                        s = tW + e; d = (lb < 64) ? (wB + e) : (wA + e + 131072); }
  else if (blk < 448) { const size_t e = (size_t)(blk - 384) * 1024; s = cWo_ + e; d = woc + e; }
  else if (blk < 512) { const size_t e = (size_t)(blk - 448) * 1024; s = tWo_ + e; d = wot + e; }
  else if (blk < 768) { const size_t e = (size_t)(blk - 512) * 1024; s = W1_ + e; d = w1b + e; }
  else                { const size_t e = (size_t)(blk - 768) * 1024; s = W2_ + e; d = w2b + e; }
  const int o = threadIdx.x * 4;
  const f32x4 v = *(const f32x4*)(s + o);
  u16x4 ov;
  #pragma unroll
  for (int j = 0; j < 4; ++j) ov[j] = f2bf(v[j]);
  *(u16x4*)(d + o) = ov;
}

// ---------- kernel 1: compaction ranks + pad zeroing ----------
__global__ __launch_bounds__(1024) void compact_kernel(
    const int* __restrict__ labels, int* __restrict__ qcnt_c,
    int* __restrict__ qcnt_t, int* __restrict__ slotm,
    u16* __restrict__ xnc, u16* __restrict__ xnt)
{
  const int b = blockIdx.x, tid = threadIdx.x;
  const int wave = tid >> 6, lane = tid & 63;
  const bool ic = labels[b * 1024 + tid] > 0;
  const unsigned long long mask = __ballot(ic);
  const int lower = __popcll(mask & ((1ull << lane) - 1ull));
  const int wc = __popcll(mask);
  __shared__ int wcnt[16], woff[17];
  if (lane == 0) wcnt[wave] = wc;
  __syncthreads();
  if (tid == 0) {
    int acc = 0;
    #pragma unroll
    for (int i = 0; i < 16; ++i) { woff[i] = acc; acc += wcnt[i]; }
    woff[16] = acc;
  }
  __syncthreads();
  const int nc = woff[16], nt = 1024 - nc;
  const int rank = ic ? (woff[wave] + lower) : (tid - woff[wave] - lower);
  slotm[b * 1024 + tid] = rank;
  if (tid == 0) { qcnt_c[b] = nc; qcnt_t[b] = nt; }
  // zero GEMM pad rows so K/V of pad slots are defined (bias) and maskable
  const int nc4 = nc + 4;
  const int needA = (nc4 + 127) & ~127;
  const int needB = (nt + 127) & ~127;
  const u16x8 z8 = {0, 0, 0, 0, 0, 0, 0, 0};
  for (int idx = tid; idx < (needA - nc4) * 32; idx += 1024)
    *(u16x8*)&xnc[((size_t)b * 1152 + nc4 + (idx >> 5)) * 256 + (idx & 31) * 8] = z8;
  for (int idx = tid; idx < (needB - nt) * 32; idx += 1024)
    *(u16x8*)&xnt[((size_t)b * 1024 + nt + (idx >> 5)) * 256 + (idx & 31) * 8] = z8;
}

// ---------- kernel 2: embed + rope2d + LN -> compacted destinations ----------
__global__ __launch_bounds__(256) void prep_kernel(
    const float* __restrict__ x, const int* __restrict__ coords,
    const int* __restrict__ labels, const float* __restrict__ tgt_e,
    const float* __restrict__ ctx_e, const float* __restrict__ regs,
    const float* __restrict__ rope, const float* __restrict__ g,
    const float* __restrict__ bt, const int* __restrict__ slotm,
    float* __restrict__ x0, u16* __restrict__ xnc, u16* __restrict__ xnt)
{
  const int wv = threadIdx.x >> 6, lane = threadIdx.x & 63;
  const int t = blockIdx.x * 4 + wv;   // 0..8223
  const int d = lane * 4;
  const int b = t / 1028, l = t - b * 1028;
  f32x4 v;
  u16* dst;
  if (l < 4) {
    const f32x4 rg = *(const f32x4*)&regs[l * 256 + d];
    const f32x4 ce = *(const f32x4*)&ctx_e[d];
    #pragma unroll
    for (int j = 0; j < 4; ++j) v[j] = rg[j] + ce[j];
    dst = &xnc[((size_t)b * 1152 + l) * 256];
  } else {
    const int p = l - 4;
    const bool ic = labels[b * 1024 + p] > 0;
    const float* emb = ic ? ctx_e : tgt_e;
    const int cy = coords[(b * 1024 + p) * 2 + 0];
    const int cx = coords[(b * 1024 + p) * 2 + 1];
    const float fy = fminf(fmaxf(((float)cy / 224.0f) * 1023.0f, 0.0f), 1023.0f);
    const float fx = fminf(fmaxf(((float)cx / 224.0f) * 1023.0f, 0.0f), 1023.0f);
    const int yi = (int)fy, xi = (int)fx;
    const bool second = d >= 128;
    const int ci = second ? yi : xi;
    const int pairi = (d & 127) >> 1;
    const f32x4 rr = *(const f32x4*)&rope[ci * 128 + pairi * 2];  // cA sA cB sB
    const int i0 = (second ? 128 : 0) + pairi * 2;
    const size_t base = (size_t)(b * 1024 + p) * 256;
    const f32x4 xv = *(const f32x4*)&x[base + i0];
    const f32x4 ev = *(const f32x4*)&emb[i0];
    const float p0 = xv[0] + ev[0], p1 = xv[1] + ev[1];
    const float p2 = xv[2] + ev[2], p3 = xv[3] + ev[3];
    v[0] = p0 * rr[0] - p1 * rr[1];
    v[1] = p0 * rr[1] + p1 * rr[0];
    v[2] = p2 * rr[2] - p3 * rr[3];
    v[3] = p2 * rr[3] + p3 * rr[2];
    const int rank = slotm[b * 1024 + p];
    dst = ic ? &xnc[((size_t)b * 1152 + 4 + rank) * 256]
             : &xnt[((size_t)b * 1024 + rank) * 256];
  }
  *(f32x4*)&x0[(size_t)t * 256 + d] = v;
  float s1 = v[0] + v[1] + v[2] + v[3];
  #pragma unroll
  for (int off = 1; off < 64; off <<= 1) s1 += __shfl_xor(s1, off);
  const float mean = s1 * (1.0f / 256.0f);
  f32x4 dv;
  float s2 = 0.f;
  #pragma unroll
  for (int j = 0; j < 4; ++j) { dv[j] = v[j] - mean; s2 += dv[j] * dv[j]; }
  #pragma unroll
  for (int off = 1; off < 64; off <<= 1) s2 += __shfl_xor(s2, off);
  const float rstd = rsqrtf(s2 * (1.0f / 256.0f) + 1e-5f);
  const f32x4 gv = *(const f32x4*)&g[d];
  const f32x4 bv = *(const f32x4*)&bt[d];
  u16x4 o;
  #pragma unroll
  for (int j = 0; j < 4; ++j) o[j] = f2bf(dv[j] * rstd * gv[j] + bv[j]);
  *(u16x4*)&dst[d] = o;
}

// ---------- generic GEMM: C[M,N] = A[M,K] @ W[N,K]^T + bias ----------
// EPI: 0 store; 1 gelu store; 2 +resid store. bcnt: per-1024-row-batch dyn-M.
template <int EPI, typename CT>
__global__ __launch_bounds__(256) void gemm_bt(
    const u16* __restrict__ A, int lda, const u16* __restrict__ W, int K,
    const float* __restrict__ bias, CT* __restrict__ C, int ldc, int M,
    const float* __restrict__ resid, const int* __restrict__ bcnt)
{
  const int mbase = blockIdx.y * 128, nbase = blockIdx.x * 128;
  if (bcnt) {
    const int need = (bcnt[mbase >> 10] + 127) & ~127;
    if ((mbase & 1023) >= need) return;
  }
  __shared__ u16 As[128 * 32];
  __shared__ u16 Bs[128 * 32];
  const int tid = threadIdx.x, lane = tid & 63, w = tid >> 6;
  const int quad = lane >> 4, r = lane & 15;
  const int wm = w >> 1, wn = w & 1;
  const int rA = lane >> 2, cA = (lane & 3) * 8;

  f32x4 acc[4][4];
  #pragma unroll
  for (int i = 0; i < 4; ++i)
    #pragma unroll
    for (int j = 0; j < 4; ++j) acc[i][j] = (f32x4){0.f, 0.f, 0.f, 0.f};

  const int nkt = K >> 5;
  for (int kt = 0; kt < nkt; ++kt) {
    const int k0 = kt * 32;
    #pragma unroll
    for (int j = 0; j < 2; ++j) {
      const int rr = w * 32 + j * 16;
      g2lds16(&A[(size_t)(mbase + rr + rA) * lda + k0 + cA], &As[rr * 32]);
      g2lds16(&W[(size_t)(nbase + rr + rA) * K + k0 + cA], &Bs[rr * 32]);
    }
    __syncthreads();
    u16x8 av[4], bv[4];
    #pragma unroll
    for (int mi = 0; mi < 4; ++mi) av[mi] = ld8(&As[(wm * 64 + mi * 16 + r) * 32 + quad * 8]);
    #pragma unroll
    for (int ni = 0; ni < 4; ++ni) bv[ni] = ld8(&Bs[(wn * 64 + ni * 16 + r) * 32 + quad * 8]);
    #pragma unroll
    for (int mi = 0; mi < 4; ++mi)
      #pragma unroll
      for (int ni = 0; ni < 4; ++ni)
        acc[mi][ni] = mfma_bf16(av[mi], bv[ni], acc[mi][ni]);
    __syncthreads();
  }

  #pragma unroll
  for (int mi = 0; mi < 4; ++mi) {
    #pragma unroll
    for (int ni = 0; ni < 4; ++ni) {
      const int col = nbase + wn * 64 + ni * 16 + r;
      const float bs = bias[col];
      const int row0 = mbase + wm * 64 + mi * 16 + quad * 4;
      #pragma unroll
      for (int i = 0; i < 4; ++i) {
        const int rr2 = row0 + i;
        if (rr2 < M) {
          float v = acc[mi][ni][i] + bs;
          if (EPI == 1) v = 0.5f * v * (1.0f + fast_erf(v * 0.70710678118654752f));
          if (EPI == 2) v += resid[(size_t)rr2 * ldc + col];
          stc(&C[(size_t)rr2 * ldc + col], v);
        }
      }
    }
  }
}

// ---------- ctx QKV GEMM: A=xnc[8x1152], N=1280; epilogue scatters K/V dense ----------
__global__ __launch_bounds__(256) void gemm_qkvA(
    const u16* __restrict__ A, const u16* __restrict__ W,
    const float* __restrict__ bias, u16* __restrict__ qc,
    u16* __restrict__ kbuf, u16* __restrict__ vbufT,
    const int* __restrict__ qcnt_c)
{
  const int bidy = blockIdx.y;           // 0..71 = b*9 + mt
  const int b = bidy / 9, mt = bidy - b * 9;
  const int need = (qcnt_c[b] + 4 + 127) & ~127;
  if (mt * 128 >= need) return;
  const int mbase = b * 1152 + mt * 128;
  const int nbase = blockIdx.x * 128;

  __shared__ u16 As[128 * 32];
  __shared__ u16 Bs[128 * 32];
  const int tid = threadIdx.x, lane = tid & 63, w = tid >> 6;
  const int quad = lane >> 4, r = lane & 15;
  const int wm = w >> 1, wn = w & 1;
  const int rA = lane >> 2, cA = (lane & 3) * 8;

  f32x4 acc[4][4];
  #pragma unroll
  for (int i = 0; i < 4; ++i)
    #pragma unroll
    for (int j = 0; j < 4; ++j) acc[i][j] = (f32x4){0.f, 0.f, 0.f, 0.f};

  for (int kt = 0; kt < 8; ++kt) {
    const int k0 = kt * 32;
    #pragma unroll
    for (int j = 0; j < 2; ++j) {
      const int rr = w * 32 + j * 16;
      g2lds16(&A[(size_t)(mbase + rr + rA) * 256 + k0 + cA], &As[rr * 32]);
      g2lds16(&W[(size_t)(nbase + rr + rA) * 256 + k0 + cA], &Bs[rr * 32]);
    }
    __syncthreads();
    u16x8 av[4], bv[4];
    #pragma unroll
    for (int mi = 0; mi < 4; ++mi) av[mi] = ld8(&As[(wm * 64 + mi * 16 + r) * 32 + quad * 8]);
    #pragma unroll
    for (int ni = 0; ni < 4; ++ni) bv[ni] = ld8(&Bs[(wn * 64 + ni * 16 + r) * 32 + quad * 8]);
    #pragma unroll
    for (int mi = 0; mi < 4; ++mi)
      #pragma unroll
      for (int ni = 0; ni < 4; ++ni)
        acc[mi][ni] = mfma_bf16(av[mi], bv[ni], acc[mi][ni]);
    __syncthreads();
  }

  #pragma unroll
  for (int mi = 0; mi < 4; ++mi) {
    #pragma unroll
    for (int ni = 0; ni < 4; ++ni) {
      const int col = nbase + wn * 64 + ni * 16 + r;
      const float bs = bias[col];
      const int row0 = mbase + wm * 64 + mi * 16 + quad * 4;
      const int slot0 = row0 - b * 1152;
      if (col < 256) {                       // q_c, row-major [9216][256]
        #pragma unroll
        for (int i = 0; i < 4; ++i)
          qc[(size_t)(row0 + i) * 256 + col] = f2bf(acc[mi][ni][i] + bs);
      } else {
        const int u = col - 256;
        const int z = u >> 9, kv = (u >> 8) & 1, h = (u >> 5) & 7, d = u & 31;
        const size_t zbh = (size_t)(z * 8 + b) * 8 + h;
        if (kv == 0) {                       // K: [zbh][slot][32]
          u16* kp = kbuf + zbh * 36864 + (size_t)slot0 * 32 + d;
          #pragma unroll
          for (int i = 0; i < 4; ++i) kp[i * 32] = f2bf(acc[mi][ni][i] + bs);
        } else {                             // V^T: [zbh][d][slot]
          u16x4 o;
          #pragma unroll
          for (int i = 0; i < 4; ++i) o[i] = f2bf(acc[mi][ni][i] + bs);
          *(u16x4*)(vbufT + (zbh * 32 + d) * 1152 + slot0) = o;
        }
      }
    }
  }
}

// ---------- Wo GEMM, both branches in one dispatch (z = branch) ----------
__global__ __launch_bounds__(256) void gemm_wo(
    const u16* __restrict__ Ac, const u16* __restrict__ At,
    const u16* __restrict__ Wc, const u16* __restrict__ Wt,
    const float* __restrict__ bc, const float* __restrict__ btg,
    u16* __restrict__ Cc, u16* __restrict__ Ct,
    const int* __restrict__ cnt_c, const int* __restrict__ cnt_t)
{
  const int z = blockIdx.z;
  const int mbase = blockIdx.y * 128, nbase = blockIdx.x * 128;
  const int* bcnt = z ? cnt_t : cnt_c;
  const int need = (bcnt[mbase >> 10] + 127) & ~127;
  if ((mbase & 1023) >= need) return;
  const u16* A = z ? At : Ac;
  const u16* W = z ? Wt : Wc;
  const float* bias = z ? btg : bc;
  u16* C = z ? Ct : Cc;

  __shared__ u16 As[128 * 32];
  __shared__ u16 Bs[128 * 32];
  const int tid = threadIdx.x, lane = tid & 63, w = tid >> 6;
  const int quad = lane >> 4, r = lane & 15;
  const int wm = w >> 1, wn = w & 1;
  const int rA = lane >> 2, cA = (lane & 3) * 8;

  f32x4 acc[4][4];
  #pragma unroll
  for (int i = 0; i < 4; ++i)
    #pragma unroll
    for (int j = 0; j < 4; ++j) acc[i][j] = (f32x4){0.f, 0.f, 0.f, 0.f};

  for (int kt = 0; kt < 8; ++kt) {
    const int k0 = kt * 32;
    #pragma unroll
    for (int j = 0; j < 2; ++j) {
      const int rr = w * 32 + j * 16;
      g2lds16(&A[(size_t)(mbase + rr + rA) * 256 + k0 + cA], &As[rr * 32]);
      g2lds16(&W[(size_t)(nbase + rr + rA) * 256 + k0 + cA], &Bs[rr * 32]);
    }
    __syncthreads();
    u16x8 av[4], bv[4];
    #pragma unroll
    for (int mi = 0; mi < 4; ++mi) av[mi] = ld8(&As[(wm * 64 + mi * 16 + r) * 32 + quad * 8]);
    #pragma unroll
    for (int ni = 0; ni < 4; ++ni) bv[ni] = ld8(&Bs[(wn * 64 + ni * 16 + r) * 32 + quad * 8]);
    #pragma unroll
    for (int mi = 0; mi < 4; ++mi)
      #pragma unroll
      for (int ni = 0; ni < 4; ++ni)
        acc[mi][ni] = mfma_bf16(av[mi], bv[ni], acc[mi][ni]);
    __syncthreads();
  }

  #pragma unroll
  for (int mi = 0; mi < 4; ++mi) {
    #pragma unroll
    for (int ni = 0; ni < 4; ++ni) {
      const int col = nbase + wn * 64 + ni * 16 + r;
      const float bs = bias[col];
      const int row0 = mbase + wm * 64 + mi * 16 + quad * 4;
      #pragma unroll
      for (int i = 0; i < 4; ++i)
        C[(size_t)(row0 + i) * 256 + col] = f2bf(acc[mi][ni][i] + bs);
    }
  }
}

// ---------- kernel 3: dense-layout flash attention, both branches ----------
// grid (17, 8, 8): x = fused qblock (ctx blocks then tgt blocks), y=h, z=b.
// K tiles contiguous; V^T tiles row-contiguous; mask = slot<nc+4 in-register.
__global__ __launch_bounds__(256) void attn4_kernel(
    const u16* __restrict__ qc, const u16* __restrict__ qt,
    const u16* __restrict__ kbuf, const u16* __restrict__ vbufT,
    const float* __restrict__ cbq, const float* __restrict__ tbq,
    const int* __restrict__ qcnt_c, const int* __restrict__ qcnt_t,
    u16* __restrict__ o_c, u16* __restrict__ o_t)
{
  const int qbx = blockIdx.x, h = blockIdx.y, b = blockIdx.z;
  const int nc = qcnt_c[b], nt = qcnt_t[b];
  const int cblk = (nc + 63) >> 6, tblk = (nt + 63) >> 6;
  int z, qsb, qn;
  if (qbx < cblk)            { z = 0; qsb = qbx << 6; qn = nc; }
  else if (qbx - cblk < tblk){ z = 1; qsb = (qbx - cblk) << 6; qn = nt; }
  else return;
  const int nc4 = nc + 4;
  const int ntile = (nc4 + 63) >> 6;
  const float* bq = z ? tbq : cbq;
  const u16* Q = z ? qt : qc;
  u16* obuf = z ? o_t : o_c;
  const int qrow0 = z ? (b * 1024 + qsb) : (b * 1152 + 4 + qsb);

  const int tid = threadIdx.x, lane = tid & 63, w = tid >> 6;
  const int quad = lane >> 4, r = lane & 15;
  const float scale = 0.17677669529663687f;  // 1/sqrt(32)

  __shared__ u16 Ks[64 * 32];       // [key][dim]
  __shared__ u16 Vt[32 * 66];       // [dim][key] stride 66
  __shared__ u16 Ps[4][16 * 72];    // per-wave P [q][key] stride 72

  const u16x8 qf = ld8(&Q[(size_t)(qrow0 + w * 16 + r) * 256 + h * 32 + quad * 8]);

  // zero-key init: score=q.bk*scale (per-lane q=r); l=1; acc=bv
  float s0 = 0.f;
  #pragma unroll
  for (int j = 0; j < 8; ++j) s0 += bf2f(qf[j]) * bq[256 + h * 32 + quad * 8 + j];
  s0 *= scale;
  s0 += __shfl_xor(s0, 16);
  s0 += __shfl_xor(s0, 32);
  float m_ = s0, l_ = 1.0f;
  f32x4 accA, accB;
  #pragma unroll
  for (int i = 0; i < 4; ++i) {
    accA[i] = bq[512 + h * 32 + quad * 4 + i];
    accB[i] = bq[512 + h * 32 + 16 + quad * 4 + i];
  }

  const size_t zbh = (size_t)(z * 8 + b) * 8 + h;
  const u16* kz = kbuf + zbh * 36864;    // [slot][32]
  const u16* vz = vbufT + zbh * 36864;   // [d][1152]
  const int dloc = (w << 3) + (lane >> 3), part = lane & 7;

  for (int t = 0; t < ntile; ++t) {
    __syncthreads();                 // protect Ks/Vt from prior readers
    g2lds16(&kz[t * 2048 + w * 512 + lane * 8], &Ks[w * 512]);   // contig 1KB/wave
    const u16x8 vv = ld8(&vz[(size_t)dloc * 1152 + t * 64 + part * 8]);
    *(u16x8*)&Vt[dloc * 66 + part * 8] = vv;
    __syncthreads();

    f32x4 sT[4];
    #pragma unroll
    for (int tt = 0; tt < 4; ++tt) {
      const u16x8 kf = ld8(&Ks[(tt * 16 + r) * 32 + quad * 8]);
      sT[tt] = mfma_bf16(kf, qf, (f32x4){0.f, 0.f, 0.f, 0.f});
    }
    const int kb0 = t * 64 + quad * 4;
    float rm = -3.0e38f;
    float sc[4][4];
    #pragma unroll
    for (int tt = 0; tt < 4; ++tt)
      #pragma unroll
      for (int i = 0; i < 4; ++i) {
        const float kbias = (kb0 + tt * 16 + i < nc4) ? 0.0f : -1e30f;
        sc[tt][i] = sT[tt][i] * scale + kbias;
        rm = fmaxf(rm, sc[tt][i]);
      }
    rm = fmaxf(rm, __shfl_xor(rm, 16));
    rm = fmaxf(rm, __shfl_xor(rm, 32));
    const float mn = fmaxf(m_, rm);
    const float al = __expf(m_ - mn);
    m_ = mn;
    float rs = 0.f;
    u16* ps = &Ps[w][r * 72];
    #pragma unroll
    for (int tt = 0; tt < 4; ++tt) {
      u16x4 pk;
      #pragma unroll
      for (int i = 0; i < 4; ++i) {
        const float pv = __expf(sc[tt][i] - mn);
        rs += pv;
        pk[i] = f2bf(pv);
      }
      *(u16x4*)&ps[tt * 16 + quad * 4] = pk;
    }
    rs += __shfl_xor(rs, 16);
    rs += __shfl_xor(rs, 32);
    l_ = l_ * al + rs;
    #pragma unroll
    for (int i = 0; i < 4; ++i) { accA[i] *= al; accB[i] *= al; }
    #pragma unroll
    for (int kk = 0; kk < 2; ++kk) {
      const u16x8 pf = ld8(&Ps[w][r * 72 + kk * 32 + quad * 8]);
      const u16x8 vf0 = ld8(&Vt[r * 66 + kk * 32 + quad * 8]);
      const u16x8 vf1 = ld8(&Vt[(16 + r) * 66 + kk * 32 + quad * 8]);
      accA = mfma_bf16(vf0, pf, accA);
      accB = mfma_bf16(vf1, pf, accB);
    }
  }

  const int qlocal = qsb + w * 16 + r;
  if (qlocal < qn) {
    const float inv = 1.0f / l_;
    u16x4 oa, ob;
    #pragma unroll
    for (int i = 0; i < 4; ++i) { oa[i] = f2bf(accA[i] * inv); ob[i] = f2bf(accB[i] * inv); }
    const size_t orow = (size_t)b * 1024 + qlocal;
    *(u16x4*)&obuf[orow * 256 + h * 32 + quad * 4] = oa;
    *(u16x4*)&obuf[orow * 256 + h * 32 + 16 + quad * 4] = ob;
  }
}

// ---------- kernel 4: branch select + residual + LN (wave-per-row) ----------
__global__ __launch_bounds__(256) void select_ln_kernel(
    const float* __restrict__ x0, const u16* __restrict__ po_c,
    const u16* __restrict__ po_t, const int* __restrict__ labels,
    const int* __restrict__ slotm, const float* __restrict__ g,
    const float* __restrict__ bt, float* __restrict__ x1,
    u16* __restrict__ hln)
{
  const int wv = threadIdx.x >> 6, lane = threadIdx.x & 63;
  const int t = blockIdx.x * 4 + wv;          // 0..8191
  const int d = lane * 4;
  const int b = t >> 10;
  const size_t row = (size_t)b * 1028 + 4 + (t & 1023);
  const bool ic = labels[t] > 0;
  const u16* po = ic ? po_c : po_t;
  const int slot = slotm[t];
  const f32x4 xv = *(const f32x4*)&x0[row * 256 + d];
  const u16x4 pv = *(const u16x4*)&po[((size_t)b * 1024 + slot) * 256 + d];
  f32x4 v;
  #pragma unroll
  for (int j = 0; j < 4; ++j) v[j] = xv[j] + bf2f(pv[j]);
  *(f32x4*)&x1[(size_t)t * 256 + d] = v;
  float s1 = v[0] + v[1] + v[2] + v[3];
  #pragma unroll
  for (int off = 1; off < 64; off <<= 1) s1 += __shfl_xor(s1, off);
  const float mean = s1 * (1.0f / 256.0f);
  f32x4 dv;
  float s2 = 0.f;
  #pragma unroll
  for (int j = 0; j < 4; ++j) { dv[j] = v[j] - mean; s2 += dv[j] * dv[j]; }
  #pragma unroll
  for (int off = 1; off < 64; off <<= 1) s2 += __shfl_xor(s2, off);
  const float rstd = rsqrtf(s2 * (1.0f / 256.0f) + 1e-5f);
  const f32x4 gv = *(const f32x4*)&g[d];
  const f32x4 bv = *(const f32x4*)&bt[d];
  u16x4 o;
  #pragma unroll
  for (int j = 0; j < 4; ++j) o[j] = f2bf(dv[j] * rstd * gv[j] + bv[j]);
  *(u16x4*)&hln[(size_t)t * 256 + d] = o;
}

// ---------- launch ----------
extern "C" void kernel_launch(void* const* d_in, const int* in_sizes, int n_in,
                              void* d_out, int out_size, void* d_ws, size_t ws_size,
                              hipStream_t stream) {
  const float* x      = (const float*)d_in[0];
  const int*   coords = (const int*)d_in[1];
  const int*   labels = (const int*)d_in[2];
  const float* tgt_e  = (const float*)d_in[3];
  const float* ctx_e  = (const float*)d_in[4];
  const float* regs   = (const float*)d_in[5];
  const float* rope   = (const float*)d_in[6];
  const float* ng     = (const float*)d_in[7];
  const float* nb     = (const float*)d_in[8];
  const float* cWqkv  = (const float*)d_in[9];
  const float* cbqkv  = (const float*)d_in[10];
  const float* cWo    = (const float*)d_in[11];
  const float* cbo    = (const float*)d_in[12];
  const float* tWqkv  = (const float*)d_in[13];
  const float* tbqkv  = (const float*)d_in[14];
  const float* tWo    = (const float*)d_in[15];
  const float* tbo    = (const float*)d_in[16];
  const float* mg     = (const float*)d_in[17];
  const float* mbeta  = (const float*)d_in[18];
  const float* W1     = (const float*)d_in[19];
  const float* b1     = (const float*)d_in[20];
  const float* W2     = (const float*)d_in[21];
  const float* b2     = (const float*)d_in[22];

  char* ws = (char*)d_ws;
  float* x0     = (float*)(ws + 0);            // 8224x256 f32  (8,421,376)
  u16*   qc     = (u16*)  (ws + 8421376);      // 9216x256 bf16 (4,718,592)
  u16*   xnc    = (u16*)  (ws + 13139968);     // 9216x256 bf16 (4,718,592)
  u16*   xnt    = (u16*)  (ws + 17858560);     // 8192x256 bf16 (4,194,304)
  u16*   qt     = (u16*)  (ws + 22052864);     // 8192x256 bf16 (4,194,304)
  u16*   kbuf   = (u16*)  (ws + 26247168);     // 2x8x8x1152x32 (9,437,184)
  u16*   vbufT  = (u16*)  (ws + 35684352);     // 2x8x8x32x1152 (9,437,184)
  u16*   o_c    = (u16*)  (ws + 45121536);     // 8192x256 bf16
  u16*   o_t    = (u16*)  (ws + 49315840);
  u16*   wA     = (u16*)  (ws + 57704448);     // 1280x256
  u16*   wB     = (u16*)  (ws + 58359808);     // 256x256
  u16*   woc    = (u16*)  (ws + 58490880);
  u16*   wot    = (u16*)  (ws + 58621952);
  u16*   w1b    = (u16*)  (ws + 58753024);     // 1024x256
  u16*   w2b    = (u16*)  (ws + 59277312);     // 256x1024
  float* bA     = (float*)(ws + 59801600);     // 1280
  float* bB     = (float*)(ws + 59806720);     // 256
  int*   slotm  = (int*)  (ws + 59807744);     // 8192
  int*   qcnt_c = (int*)  (ws + 59840512);     // 8
  int*   qcnt_t = (int*)  (ws + 59840544);     // 8  -> end 59,840,576
  // aliases over dead regions:
  u16*   po_c   = (u16*)  (ws + 8421376);      // over qc (dead after attn)
  u16*   po_t   = (u16*)  (ws + 13139968);     // over xnc (dead after qkvA)
  u16*   hmid   = (u16*)  (ws + 22052864);     // over qt+kbuf+vbuf head (16.8 MB)
  u16*   hln    = (u16*)  (ws + 45121536);     // over o_c (dead after wo)
  float* x1     = (float*)(ws + 49315840);     // over o_t.. (8,388,608 -> 57,704,448)

  cvt_kernel<<<dim3(1026), 256, 0, stream>>>(cWqkv, tWqkv, cWo, tWo, W1, W2,
                                             cbqkv, tbqkv,
                                             wA, wB, woc, wot, w1b, w2b, bA, bB);
  compact_kernel<<<dim3(8), 1024, 0, stream>>>(labels, qcnt_c, qcnt_t, slotm, xnc, xnt);
  prep_kernel<<<dim3(2056), 256, 0, stream>>>(x, coords, labels, tgt_e, ctx_e,
                                              regs, rope, ng, nb, slotm, x0, xnc, xnt);
  gemm_qkvA<<<dim3(10, 72), 256, 0, stream>>>(xnc, wA, bA, qc, kbuf, vbufT, qcnt_c);
  gemm_bt<0, u16><<<dim3(2, 64), 256, 0, stream>>>(xnt, 256, wB, 256, bB, qt, 256, 8192, nullptr, qcnt_t);
  attn4_kernel<<<dim3(17, 8, 8), 256, 0, stream>>>(qc, qt, kbuf, vbufT, cbqkv, tbqkv,
                                                   qcnt_c, qcnt_t, o_c, o_t);
  gemm_wo<<<dim3(2, 64, 2), 256, 0, stream>>>(o_c, o_t, woc, wot, cbo, tbo, po_c, po_t, qcnt_c, qcnt_t);
  select_ln_kernel<<<dim3(2048), 256, 0, stream>>>(x0, po_c, po_t, labels, slotm, mg, mbeta, x1, hln);
  gemm_bt<1, u16><<<dim3(8, 64), 256, 0, stream>>>(hln, 256, w1b, 256, b1, hmid, 1024, 8192, nullptr, nullptr);
  gemm_bt<2, float><<<dim3(2, 64), 256, 0, stream>>>(hmid, 1024, w2b, 1024, b2, (float*)d_out, 256, 8192, x1, nullptr);
}

// Round 8
// 222.928 us; speedup vs baseline: 1.2452x; 1.1222x over previous
//
#include <hip/hip_runtime.h>
#include <stdint.h>
#include <stddef.h>

typedef unsigned short u16;
typedef __bf16 bf16t;
typedef bf16t bf16x8 __attribute__((ext_vector_type(8)));
typedef u16 u16x8 __attribute__((ext_vector_type(8)));
typedef u16 u16x4 __attribute__((ext_vector_type(4)));
typedef float f32x4 __attribute__((ext_vector_type(4)));

// ---------- helpers ----------
__device__ __forceinline__ float bf2f(u16 u) {
  unsigned int x = ((unsigned int)u) << 16;
  return __builtin_bit_cast(float, x);
}
__device__ __forceinline__ u16 f2bf(float f) {
  unsigned int x = __builtin_bit_cast(unsigned int, f);
  x += 0x7fffu + ((x >> 16) & 1u);
  return (u16)(x >> 16);
}
__device__ __forceinline__ u16x8 ld8(const u16* p) { return *(const u16x8*)p; }

__device__ __forceinline__ f32x4 mfma_bf16(u16x8 a, u16x8 b, f32x4 c) {
  return __builtin_amdgcn_mfma_f32_16x16x32_bf16(
      __builtin_bit_cast(bf16x8, a), __builtin_bit_cast(bf16x8, b), c, 0, 0, 0);
}
__device__ __forceinline__ void g2lds16(const u16* g, u16* l) {
  __builtin_amdgcn_global_load_lds(
      (const __attribute__((address_space(1))) unsigned int*)g,
      (__attribute__((address_space(3))) unsigned int*)l, 16, 0, 0);
}
__device__ __forceinline__ void stc(u16* p, float v) { *p = f2bf(v); }
__device__ __forceinline__ void stc(float* p, float v) { *p = v; }

// erf via Abramowitz–Stegun 7.1.26 (|err|<=1.5e-7), one __expf
__device__ __forceinline__ float fast_erf(float x) {
  const float ax = fabsf(x);
  const float t = 1.0f / (1.0f + 0.3275911f * ax);
  const float y = 1.0f - (((((1.061405429f * t - 1.453152027f) * t) + 1.421413741f) * t
                  - 0.284496736f) * t + 0.254829592f) * t * __expf(-ax * ax);
  return copysignf(y, x);
}

// ---------- constants ----------
// B=8 K=1024 D=256 H=8 hd=32 R=4 L=1028 Ltok=8224
// xnc [8][1152][256] (rows 0-3 regs, 4..nc+3 ctx tokens, pad 0), xnt [8][1024][256].
// ctx GEMM N=1280 = [q_c k_c v_c k_t v_t]; K/V dense per-head:
//   kbuf[z][b][h][slot<1152][32], vbufT[z][b][h][d<32][slot<1152]

// ---------- kernel 0: weights->bf16 + biases + compaction (merged) ----------
__global__ __launch_bounds__(256) void cvt_kernel(
    const float* __restrict__ cW, const float* __restrict__ tW,
    const float* __restrict__ cWo_, const float* __restrict__ tWo_,
    const float* __restrict__ W1_, const float* __restrict__ W2_,
    const float* __restrict__ cb, const float* __restrict__ tb,
    u16* __restrict__ wA, u16* __restrict__ wB, u16* __restrict__ woc,
    u16* __restrict__ wot, u16* __restrict__ w1b, u16* __restrict__ w2b,
    float* __restrict__ bA, float* __restrict__ bB,
    const int* __restrict__ labels, int* __restrict__ slotm,
    int* __restrict__ qcnt_c, int* __restrict__ qcnt_t,
    u16* __restrict__ xnc, u16* __restrict__ xnt)
{
  const int blk = blockIdx.x;
  const int tid = threadIdx.x;
  if (blk >= 1026) {                         // compaction for batch b (8 blocks)
    const int b = blk - 1026;
    const int wave = tid >> 6, lane = tid & 63;
    __shared__ int wcnt[4];
    int base_c = 0, base_t = 0;
    for (int p = 0; p < 4; ++p) {
      const int idx = p * 256 + tid;
      const bool ic = labels[b * 1024 + idx] > 0;
      const unsigned long long mk = __ballot(ic);
      const int lower = __popcll(mk & ((1ull << lane) - 1ull));
      if (lane == 0) wcnt[wave] = __popcll(mk);
      __syncthreads();
      int off = 0, tot = 0;
      #pragma unroll
      for (int i = 0; i < 4; ++i) { if (i < wave) off += wcnt[i]; tot += wcnt[i]; }
      slotm[b * 1024 + idx] = ic ? (base_c + off + lower)
                                 : (base_t + tid - off - lower);
      base_c += tot; base_t += 256 - tot;
      __syncthreads();
    }
    if (tid == 0) { qcnt_c[b] = base_c; qcnt_t[b] = base_t; }
    // zero GEMM pad rows (so K/V pad slots & staged A-tiles are defined)
    const int nc4 = base_c + 4;
    const int needA = (nc4 + 127) & ~127;
    const int needB = (base_t + 127) & ~127;
    const u16x8 z8 = {0, 0, 0, 0, 0, 0, 0, 0};
    for (int idx = tid; idx < (needA - nc4) * 32; idx += 256)
      *(u16x8*)&xnc[((size_t)b * 1152 + nc4 + (idx >> 5)) * 256 + (idx & 31) * 8] = z8;
    for (int idx = tid; idx < (needB - base_t) * 32; idx += 256)
      *(u16x8*)&xnt[((size_t)b * 1024 + base_t + (idx >> 5)) * 256 + (idx & 31) * 8] = z8;
    return;
  }
  if (blk >= 1024) {                         // bias assembly (f32)
    const int e = tid * 4;
    if (blk == 1024) {
      #pragma unroll
      for (int j = 0; j < 4; ++j) {
        const int k = e + j;
        bA[k] = (k < 768) ? cb[k] : tb[k - 512];   // [cb_q cb_k cb_v tb_k]
      }
    } else {
      #pragma unroll
      for (int j = 0; j < 4; ++j) {
        const int k = e + j;
        if (k < 256) bA[1024 + k] = tb[512 + k];   // tb_v
        else if (k < 512) bB[k - 256] = tb[k - 256]; // tb_q
      }
    }
    return;
  }
  const float* s; u16* d;
  if (blk < 192)      { const size_t e = (size_t)blk * 1024; s = cW + e; d = wA + e; }
  else if (blk < 384) { const int lb = blk - 192; const size_t e = (size_t)lb * 1024;
                        s = tW + e; d = (lb < 64) ? (wB + e) : (wA + e + 131072); }
  else if (blk < 448) { const size_t e = (size_t)(blk - 384) * 1024; s = cWo_ + e; d = woc + e; }
  else if (blk < 512) { const size_t e = (size_t)(blk - 448) * 1024; s = tWo_ + e; d = wot + e; }
  else if (blk < 768) { const size_t e = (size_t)(blk - 512) * 1024; s = W1_ + e; d = w1b + e; }
  else                { const size_t e = (size_t)(blk - 768) * 1024; s = W2_ + e; d = w2b + e; }
  const int o = tid * 4;
  const f32x4 v = *(const f32x4*)(s + o);
  u16x4 ov;
  #pragma unroll
  for (int j = 0; j < 4; ++j) ov[j] = f2bf(v[j]);
  *(u16x4*)(d + o) = ov;
}

// ---------- kernel 1: embed + rope2d + LN -> compacted destinations ----------
__global__ __launch_bounds__(256) void prep_kernel(
    const float* __restrict__ x, const int* __restrict__ coords,
    const int* __restrict__ labels, const float* __restrict__ tgt_e,
    const float* __restrict__ ctx_e, const float* __restrict__ regs,
    const float* __restrict__ rope, const float* __restrict__ g,
    const float* __restrict__ bt, const int* __restrict__ slotm,
    float* __restrict__ x0, u16* __restrict__ xnc, u16* __restrict__ xnt)
{
  const int wv = threadIdx.x >> 6, lane = threadIdx.x & 63;
  const int t = blockIdx.x * 4 + wv;   // 0..8223
  const int d = lane * 4;
  const int b = t / 1028, l = t - b * 1028;
  f32x4 v;
  u16* dst;
  if (l < 4) {
    const f32x4 rg = *(const f32x4*)&regs[l * 256 + d];
    const f32x4 ce = *(const f32x4*)&ctx_e[d];
    #pragma unroll
    for (int j = 0; j < 4; ++j) v[j] = rg[j] + ce[j];
    dst = &xnc[((size_t)b * 1152 + l) * 256];
  } else {
    const int p = l - 4;
    const bool ic = labels[b * 1024 + p] > 0;
    const float* emb = ic ? ctx_e : tgt_e;
    const int cy = coords[(b * 1024 + p) * 2 + 0];
    const int cx = coords[(b * 1024 + p) * 2 + 1];
    const float fy = fminf(fmaxf(((float)cy / 224.0f) * 1023.0f, 0.0f), 1023.0f);
    const float fx = fminf(fmaxf(((float)cx / 224.0f) * 1023.0f, 0.0f), 1023.0f);
    const int yi = (int)fy, xi = (int)fx;
    const bool second = d >= 128;
    const int ci = second ? yi : xi;
    const int pairi = (d & 127) >> 1;
    const f32x4 rr = *(const f32x4*)&rope[ci * 128 + pairi * 2];  // cA sA cB sB
    const int i0 = (second ? 128 : 0) + pairi * 2;
    const size_t base = (size_t)(b * 1024 + p) * 256;
    const f32x4 xv = *(const f32x4*)&x[base + i0];
    const f32x4 ev = *(const f32x4*)&emb[i0];
    const float p0 = xv[0] + ev[0], p1 = xv[1] + ev[1];
    const float p2 = xv[2] + ev[2], p3 = xv[3] + ev[3];
    v[0] = p0 * rr[0] - p1 * rr[1];
    v[1] = p0 * rr[1] + p1 * rr[0];
    v[2] = p2 * rr[2] - p3 * rr[3];
    v[3] = p2 * rr[3] + p3 * rr[2];
    const int rank = slotm[b * 1024 + p];
    dst = ic ? &xnc[((size_t)b * 1152 + 4 + rank) * 256]
             : &xnt[((size_t)b * 1024 + rank) * 256];
  }
  *(f32x4*)&x0[(size_t)t * 256 + d] = v;
  float s1 = v[0] + v[1] + v[2] + v[3];
  #pragma unroll
  for (int off = 1; off < 64; off <<= 1) s1 += __shfl_xor(s1, off);
  const float mean = s1 * (1.0f / 256.0f);
  f32x4 dv;
  float s2 = 0.f;
  #pragma unroll
  for (int j = 0; j < 4; ++j) { dv[j] = v[j] - mean; s2 += dv[j] * dv[j]; }
  #pragma unroll
  for (int off = 1; off < 64; off <<= 1) s2 += __shfl_xor(s2, off);
  const float rstd = rsqrtf(s2 * (1.0f / 256.0f) + 1e-5f);
  const f32x4 gv = *(const f32x4*)&g[d];
  const f32x4 bv = *(const f32x4*)&bt[d];
  u16x4 o;
  #pragma unroll
  for (int j = 0; j < 4; ++j) o[j] = f2bf(dv[j] * rstd * gv[j] + bv[j]);
  *(u16x4*)&dst[d] = o;
}

// ---------- generic GEMM: C[M,N] = A[M,K] @ W[N,K]^T + bias ----------
// MI: rows/wave/16 (tile M = MI*32). EPI: 0 store; 1 gelu; 2 +resid.
template <int MI, int EPI, typename CT>
__global__ __launch_bounds__(256) void gemm_bt(
    const u16* __restrict__ A, int lda, const u16* __restrict__ W, int K,
    const float* __restrict__ bias, CT* __restrict__ C, int ldc, int M,
    const float* __restrict__ resid)
{
  constexpr int TM = MI * 32;
  const int mbase = blockIdx.y * TM, nbase = blockIdx.x * 128;
  __shared__ u16 As[TM * 32];
  __shared__ u16 Bs[128 * 32];
  const int tid = threadIdx.x, lane = tid & 63, w = tid >> 6;
  const int quad = lane >> 4, r = lane & 15;
  const int wm = w >> 1, wn = w & 1;
  const int rA = lane >> 2, cA = (lane & 3) * 8;

  f32x4 acc[MI][4];
  #pragma unroll
  for (int i = 0; i < MI; ++i)
    #pragma unroll
    for (int j = 0; j < 4; ++j) acc[i][j] = (f32x4){0.f, 0.f, 0.f, 0.f};

  const int nkt = K >> 5;
  for (int kt = 0; kt < nkt; ++kt) {
    const int k0 = kt * 32;
    #pragma unroll
    for (int j = 0; j < MI / 2; ++j) {
      const int rr = w * (MI * 8) + j * 16;
      g2lds16(&A[(size_t)(mbase + rr + rA) * lda + k0 + cA], &As[rr * 32]);
    }
    #pragma unroll
    for (int j = 0; j < 2; ++j) {
      const int rr = w * 32 + j * 16;
      g2lds16(&W[(size_t)(nbase + rr + rA) * K + k0 + cA], &Bs[rr * 32]);
    }
    __syncthreads();
    u16x8 av[MI], bv[4];
    #pragma unroll
    for (int mi = 0; mi < MI; ++mi) av[mi] = ld8(&As[(wm * (MI * 16) + mi * 16 + r) * 32 + quad * 8]);
    #pragma unroll
    for (int ni = 0; ni < 4; ++ni) bv[ni] = ld8(&Bs[(wn * 64 + ni * 16 + r) * 32 + quad * 8]);
    #pragma unroll
    for (int mi = 0; mi < MI; ++mi)
      #pragma unroll
      for (int ni = 0; ni < 4; ++ni)
        acc[mi][ni] = mfma_bf16(av[mi], bv[ni], acc[mi][ni]);
    __syncthreads();
  }

  #pragma unroll
  for (int mi = 0; mi < MI; ++mi) {
    #pragma unroll
    for (int ni = 0; ni < 4; ++ni) {
      const int col = nbase + wn * 64 + ni * 16 + r;
      const float bs = bias[col];
      const int row0 = mbase + wm * (MI * 16) + mi * 16 + quad * 4;
      #pragma unroll
      for (int i = 0; i < 4; ++i) {
        const int rr2 = row0 + i;
        if (rr2 < M) {
          float v = acc[mi][ni][i] + bs;
          if (EPI == 1) v = 0.5f * v * (1.0f + fast_erf(v * 0.70710678118654752f));
          if (EPI == 2) v += resid[(size_t)rr2 * ldc + col];
          stc(&C[(size_t)rr2 * ldc + col], v);
        }
      }
    }
  }
}

// ---------- fused QKV GEMM: ctx (y<72, N=1280, scatters K/V) + tgt-q (y>=72) ----------
__global__ __launch_bounds__(256) void gemm_qkv(
    const u16* __restrict__ xnc, const u16* __restrict__ xnt,
    const u16* __restrict__ wA, const u16* __restrict__ wB,
    const float* __restrict__ bA, const float* __restrict__ bB,
    u16* __restrict__ qc, u16* __restrict__ qt,
    u16* __restrict__ kbuf, u16* __restrict__ vbufT,
    const int* __restrict__ qcnt_c, const int* __restrict__ qcnt_t)
{
  const int y = blockIdx.y;
  const int nbase = blockIdx.x * 128;
  const u16 *Ap, *Wp; const float* bp;
  int mbase, b;
  bool tgt;
  if (y < 72) {
    tgt = false;
    b = y / 9; const int mt = y - b * 9;
    const int need = (qcnt_c[b] + 4 + 127) & ~127;
    if (mt * 128 >= need) return;
    mbase = b * 1152 + mt * 128;
    Ap = xnc; Wp = wA; bp = bA;
  } else {
    if (nbase >= 256) return;
    tgt = true;
    const int yy = y - 72;
    b = yy >> 3; const int mt = yy & 7;
    const int need = (qcnt_t[b] + 127) & ~127;
    if (mt * 128 >= need) return;
    mbase = b * 1024 + mt * 128;
    Ap = xnt; Wp = wB; bp = bB;
  }

  __shared__ u16 As[128 * 32];
  __shared__ u16 Bs[128 * 32];
  const int tid = threadIdx.x, lane = tid & 63, w = tid >> 6;
  const int quad = lane >> 4, r = lane & 15;
  const int wm = w >> 1, wn = w & 1;
  const int rA = lane >> 2, cA = (lane & 3) * 8;

  f32x4 acc[4][4];
  #pragma unroll
  for (int i = 0; i < 4; ++i)
    #pragma unroll
    for (int j = 0; j < 4; ++j) acc[i][j] = (f32x4){0.f, 0.f, 0.f, 0.f};

  for (int kt = 0; kt < 8; ++kt) {
    const int k0 = kt * 32;
    #pragma unroll
    for (int j = 0; j < 2; ++j) {
      const int rr = w * 32 + j * 16;
      g2lds16(&Ap[(size_t)(mbase + rr + rA) * 256 + k0 + cA], &As[rr * 32]);
      g2lds16(&Wp[(size_t)(nbase + rr + rA) * 256 + k0 + cA], &Bs[rr * 32]);
    }
    __syncthreads();
    u16x8 av[4], bv[4];
    #pragma unroll
    for (int mi = 0; mi < 4; ++mi) av[mi] = ld8(&As[(wm * 64 + mi * 16 + r) * 32 + quad * 8]);
    #pragma unroll
    for (int ni = 0; ni < 4; ++ni) bv[ni] = ld8(&Bs[(wn * 64 + ni * 16 + r) * 32 + quad * 8]);
    #pragma unroll
    for (int mi = 0; mi < 4; ++mi)
      #pragma unroll
      for (int ni = 0; ni < 4; ++ni)
        acc[mi][ni] = mfma_bf16(av[mi], bv[ni], acc[mi][ni]);
    __syncthreads();
  }

  #pragma unroll
  for (int mi = 0; mi < 4; ++mi) {
    #pragma unroll
    for (int ni = 0; ni < 4; ++ni) {
      const int col = nbase + wn * 64 + ni * 16 + r;
      const float bs = bp[col];
      const int row0 = mbase + wm * 64 + mi * 16 + quad * 4;
      if (tgt) {                             // q_t row-major [8192][256]
        #pragma unroll
        for (int i = 0; i < 4; ++i)
          qt[(size_t)(row0 + i) * 256 + col] = f2bf(acc[mi][ni][i] + bs);
      } else if (col < 256) {                // q_c row-major [9216][256]
        #pragma unroll
        for (int i = 0; i < 4; ++i)
          qc[(size_t)(row0 + i) * 256 + col] = f2bf(acc[mi][ni][i] + bs);
      } else {
        const int slot0 = row0 - b * 1152;
        const int u = col - 256;
        const int z = u >> 9, kv = (u >> 8) & 1, h = (u >> 5) & 7, d = u & 31;
        const size_t zbh = (size_t)(z * 8 + b) * 8 + h;
        if (kv == 0) {                       // K: [zbh][slot][32]
          u16* kp = kbuf + zbh * 36864 + (size_t)slot0 * 32 + d;
          #pragma unroll
          for (int i = 0; i < 4; ++i) kp[i * 32] = f2bf(acc[mi][ni][i] + bs);
        } else {                             // V^T: [zbh][d][slot]
          u16x4 o;
          #pragma unroll
          for (int i = 0; i < 4; ++i) o[i] = f2bf(acc[mi][ni][i] + bs);
          *(u16x4*)(vbufT + (zbh * 32 + d) * 1152 + slot0) = o;
        }
      }
    }
  }
}

// ---------- Wo GEMM, both branches, 64-row tiles ----------
__global__ __launch_bounds__(256) void gemm_wo(
    const u16* __restrict__ Ac, const u16* __restrict__ At,
    const u16* __restrict__ Wc, const u16* __restrict__ Wt,
    const float* __restrict__ bc, const float* __restrict__ btg,
    u16* __restrict__ Cc, u16* __restrict__ Ct,
    const int* __restrict__ cnt_c, const int* __restrict__ cnt_t)
{
  const int z = blockIdx.z;
  const int y = blockIdx.y, b = y >> 4, mt = y & 15;
  const int* bcnt = z ? cnt_t : cnt_c;
  const int need = (bcnt[b] + 63) & ~63;
  if (mt * 64 >= need) return;
  const int mbase = b * 1024 + mt * 64, nbase = blockIdx.x * 128;
  const u16* A = z ? At : Ac;
  const u16* W = z ? Wt : Wc;
  const float* bias = z ? btg : bc;
  u16* C = z ? Ct : Cc;

  __shared__ u16 As[64 * 32];
  __shared__ u16 Bs[128 * 32];
  const int tid = threadIdx.x, lane = tid & 63, w = tid >> 6;
  const int quad = lane >> 4, r = lane & 15;
  const int wm = w >> 1, wn = w & 1;
  const int rA = lane >> 2, cA = (lane & 3) * 8;

  f32x4 acc[2][4];
  #pragma unroll
  for (int i = 0; i < 2; ++i)
    #pragma unroll
    for (int j = 0; j < 4; ++j) acc[i][j] = (f32x4){0.f, 0.f, 0.f, 0.f};

  for (int kt = 0; kt < 8; ++kt) {
    const int k0 = kt * 32;
    g2lds16(&A[(size_t)(mbase + w * 16 + rA) * 256 + k0 + cA], &As[w * 512]);
    #pragma unroll
    for (int j = 0; j < 2; ++j) {
      const int rr = w * 32 + j * 16;
      g2lds16(&W[(size_t)(nbase + rr + rA) * 256 + k0 + cA], &Bs[rr * 32]);
    }
    __syncthreads();
    u16x8 av[2], bv[4];
    #pragma unroll
    for (int mi = 0; mi < 2; ++mi) av[mi] = ld8(&As[(wm * 32 + mi * 16 + r) * 32 + quad * 8]);
    #pragma unroll
    for (int ni = 0; ni < 4; ++ni) bv[ni] = ld8(&Bs[(wn * 64 + ni * 16 + r) * 32 + quad * 8]);
    #pragma unroll
    for (int mi = 0; mi < 2; ++mi)
      #pragma unroll
      for (int ni = 0; ni < 4; ++ni)
        acc[mi][ni] = mfma_bf16(av[mi], bv[ni], acc[mi][ni]);
    __syncthreads();
  }

  #pragma unroll
  for (int mi = 0; mi < 2; ++mi) {
    #pragma unroll
    for (int ni = 0; ni < 4; ++ni) {
      const int col = nbase + wn * 64 + ni * 16 + r;
      const float bs = bias[col];
      const int row0 = mbase + wm * 32 + mi * 16 + quad * 4;
      #pragma unroll
      for (int i = 0; i < 4; ++i)
        C[(size_t)(row0 + i) * 256 + col] = f2bf(acc[mi][ni][i] + bs);
    }
  }
}

// ---------- kernel 3: dense-layout flash attention, double-buffered ----------
// grid (17, 8, 8): x = fused qblock (ctx then tgt), y=h, z=b.
__global__ __launch_bounds__(256) void attn4_kernel(
    const u16* __restrict__ qc, const u16* __restrict__ qt,
    const u16* __restrict__ kbuf, const u16* __restrict__ vbufT,
    const float* __restrict__ cbq, const float* __restrict__ tbq,
    const int* __restrict__ qcnt_c, const int* __restrict__ qcnt_t,
    u16* __restrict__ o_c, u16* __restrict__ o_t)
{
  const int qbx = blockIdx.x, h = blockIdx.y, b = blockIdx.z;
  const int nc = qcnt_c[b], nt = qcnt_t[b];
  const int cblk = (nc + 63) >> 6, tblk = (nt + 63) >> 6;
  int z, qsb, qn;
  if (qbx < cblk)            { z = 0; qsb = qbx << 6; qn = nc; }
  else if (qbx - cblk < tblk){ z = 1; qsb = (qbx - cblk) << 6; qn = nt; }
  else return;
  const int nc4 = nc + 4;
  const int ntile = (nc4 + 63) >> 6;
  const float* bq = z ? tbq : cbq;
  const u16* Q = z ? qt : qc;
  u16* obuf = z ? o_t : o_c;
  const int qrow0 = z ? (b * 1024 + qsb) : (b * 1152 + 4 + qsb);

  const int tid = threadIdx.x, lane = tid & 63, w = tid >> 6;
  const int quad = lane >> 4, r = lane & 15;
  const float scale = 0.17677669529663687f;  // 1/sqrt(32)

  __shared__ u16 Ks[2][2048];       // [key][dim], double-buffered
  __shared__ u16 Vt[2][32 * 66];    // [dim][key] stride 66, double-buffered
  __shared__ u16 Ps[4][16 * 72];    // per-wave P [q][key] stride 72

  const u16x8 qf = ld8(&Q[(size_t)(qrow0 + w * 16 + r) * 256 + h * 32 + quad * 8]);

  // zero-key init
  float s0 = 0.f;
  #pragma unroll
  for (int j = 0; j < 8; ++j) s0 += bf2f(qf[j]) * bq[256 + h * 32 + quad * 8 + j];
  s0 *= scale;
  s0 += __shfl_xor(s0, 16);
  s0 += __shfl_xor(s0, 32);
  float m_ = s0, l_ = 1.0f;
  f32x4 accA, accB;
  #pragma unroll
  for (int i = 0; i < 4; ++i) {
    accA[i] = bq[512 + h * 32 + quad * 4 + i];
    accB[i] = bq[512 + h * 32 + 16 + quad * 4 + i];
  }

  const size_t zbh = (size_t)(z * 8 + b) * 8 + h;
  const u16* kz = kbuf + zbh * 36864;    // [slot][32]
  const u16* vz = vbufT + zbh * 36864;   // [d][1152]
  const int dloc = (w << 3) + (lane >> 3), part = lane & 7;

  // preload tile 0
  g2lds16(&kz[w * 512 + lane * 8], &Ks[0][w * 512]);
  u16x8 vv = ld8(&vz[(size_t)dloc * 1152 + part * 8]);

  for (int t = 0; t < ntile; ++t) {
    const int cur = t & 1, nxt = cur ^ 1;
    #pragma unroll
    for (int j = 0; j < 8; ++j) Vt[cur][dloc * 66 + part * 8 + j] = vv[j];
    __syncthreads();                 // drains K-DMA(t) + V scatter
    if (t + 1 < ntile) {             // prefetch t+1, drained at NEXT barrier
      g2lds16(&kz[(t + 1) * 2048 + w * 512 + lane * 8], &Ks[nxt][w * 512]);
      vv = ld8(&vz[(size_t)dloc * 1152 + (t + 1) * 64 + part * 8]);
    }

    f32x4 sT[4];
    #pragma unroll
    for (int tt = 0; tt < 4; ++tt) {
      const u16x8 kf = ld8(&Ks[cur][(tt * 16 + r) * 32 + quad * 8]);
      sT[tt] = mfma_bf16(kf, qf, (f32x4){0.f, 0.f, 0.f, 0.f});
    }
    const int kb0 = t * 64 + quad * 4;
    float rm = -3.0e38f;
    float sc[4][4];
    #pragma unroll
    for (int tt = 0; tt < 4; ++tt)
      #pragma unroll
      for (int i = 0; i < 4; ++i) {
        const float kbias = (kb0 + tt * 16 + i < nc4) ? 0.0f : -1e30f;
        sc[tt][i] = sT[tt][i] * scale + kbias;
        rm = fmaxf(rm, sc[tt][i]);
      }
    rm = fmaxf(rm, __shfl_xor(rm, 16));
    rm = fmaxf(rm, __shfl_xor(rm, 32));
    const float mn = fmaxf(m_, rm);
    const float al = __expf(m_ - mn);
    m_ = mn;
    float rs = 0.f;
    u16* ps = &Ps[w][r * 72];
    #pragma unroll
    for (int tt = 0; tt < 4; ++tt) {
      u16x4 pk;
      #pragma unroll
      for (int i = 0; i < 4; ++i) {
        const float pv = __expf(sc[tt][i] - mn);
        rs += pv;
        pk[i] = f2bf(pv);
      }
      *(u16x4*)&ps[tt * 16 + quad * 4] = pk;
    }
    rs += __shfl_xor(rs, 16);
    rs += __shfl_xor(rs, 32);
    l_ = l_ * al + rs;
    #pragma unroll
    for (int i = 0; i < 4; ++i) { accA[i] *= al; accB[i] *= al; }
    #pragma unroll
    for (int kk = 0; kk < 2; ++kk) {
      const u16x8 pf = ld8(&Ps[w][r * 72 + kk * 32 + quad * 8]);
      const u16x8 vf0 = ld8(&Vt[cur][r * 66 + kk * 32 + quad * 8]);
      const u16x8 vf1 = ld8(&Vt[cur][(16 + r) * 66 + kk * 32 + quad * 8]);
      accA = mfma_bf16(vf0, pf, accA);
      accB = mfma_bf16(vf1, pf, accB);
    }
  }

  const int qlocal = qsb + w * 16 + r;
  if (qlocal < qn) {
    const float inv = 1.0f / l_;
    u16x4 oa, ob;
    #pragma unroll
    for (int i = 0; i < 4; ++i) { oa[i] = f2bf(accA[i] * inv); ob[i] = f2bf(accB[i] * inv); }
    const size_t orow = (size_t)b * 1024 + qlocal;
    *(u16x4*)&obuf[orow * 256 + h * 32 + quad * 4] = oa;
    *(u16x4*)&obuf[orow * 256 + h * 32 + 16 + quad * 4] = ob;
  }
}

// ---------- kernel 4: branch select + residual + LN (wave-per-row) ----------
__global__ __launch_bounds__(256) void select_ln_kernel(
    const float* __restrict__ x0, const u16* __restrict__ po_c,
    const u16* __restrict__ po_t, const int* __restrict__ labels,
    const int* __restrict__ slotm, const float* __restrict__ g,
    const float* __restrict__ bt, float* __restrict__ x1,
    u16* __restrict__ hln)
{
  const int wv = threadIdx.x >> 6, lane = threadIdx.x & 63;
  const int t = blockIdx.x * 4 + wv;          // 0..8191
  const int d = lane * 4;
  const int b = t >> 10;
  const size_t row = (size_t)b * 1028 + 4 + (t & 1023);
  const bool ic = labels[t] > 0;
  const u16* po = ic ? po_c : po_t;
  const int slot = slotm[t];
  const f32x4 xv = *(const f32x4*)&x0[row * 256 + d];
  const u16x4 pv = *(const u16x4*)&po[((size_t)b * 1024 + slot) * 256 + d];
  f32x4 v;
  #pragma unroll
  for (int j = 0; j < 4; ++j) v[j] = xv[j] + bf2f(pv[j]);
  *(f32x4*)&x1[(size_t)t * 256 + d] = v;
  float s1 = v[0] + v[1] + v[2] + v[3];
  #pragma unroll
  for (int off = 1; off < 64; off <<= 1) s1 += __shfl_xor(s1, off);
  const float mean = s1 * (1.0f / 256.0f);
  f32x4 dv;
  float s2 = 0.f;
  #pragma unroll
  for (int j = 0; j < 4; ++j) { dv[j] = v[j] - mean; s2 += dv[j] * dv[j]; }
  #pragma unroll
  for (int off = 1; off < 64; off <<= 1) s2 += __shfl_xor(s2, off);
  const float rstd = rsqrtf(s2 * (1.0f / 256.0f) + 1e-5f);
  const f32x4 gv = *(const f32x4*)&g[d];
  const f32x4 bv = *(const f32x4*)&bt[d];
  u16x4 o;
  #pragma unroll
  for (int j = 0; j < 4; ++j) o[j] = f2bf(dv[j] * rstd * gv[j] + bv[j]);
  *(u16x4*)&hln[(size_t)t * 256 + d] = o;
}

// ---------- launch ----------
extern "C" void kernel_launch(void* const* d_in, const int* in_sizes, int n_in,
                              void* d_out, int out_size, void* d_ws, size_t ws_size,
                              hipStream_t stream) {
  const float* x      = (const float*)d_in[0];
  const int*   coords = (const int*)d_in[1];
  const int*   labels = (const int*)d_in[2];
  const float* tgt_e  = (const float*)d_in[3];
  const float* ctx_e  = (const float*)d_in[4];
  const float* regs   = (const float*)d_in[5];
  const float* rope   = (const float*)d_in[6];
  const float* ng     = (const float*)d_in[7];
  const float* nb     = (const float*)d_in[8];
  const float* cWqkv  = (const float*)d_in[9];
  const float* cbqkv  = (const float*)d_in[10];
  const float* cWo    = (const float*)d_in[11];
  const float* cbo    = (const float*)d_in[12];
  const float* tWqkv  = (const float*)d_in[13];
  const float* tbqkv  = (const float*)d_in[14];
  const float* tWo    = (const float*)d_in[15];
  const float* tbo    = (const float*)d_in[16];
  const float* mg     = (const float*)d_in[17];
  const float* mbeta  = (const float*)d_in[18];
  const float* W1     = (const float*)d_in[19];
  const float* b1     = (const float*)d_in[20];
  const float* W2     = (const float*)d_in[21];
  const float* b2     = (const float*)d_in[22];

  char* ws = (char*)d_ws;
  float* x0     = (float*)(ws + 0);            // 8224x256 f32  (8,421,376)
  u16*   qc     = (u16*)  (ws + 8421376);      // 9216x256 bf16 (4,718,592)
  u16*   xnc    = (u16*)  (ws + 13139968);     // 9216x256 bf16 (4,718,592)
  u16*   xnt    = (u16*)  (ws + 17858560);     // 8192x256 bf16 (4,194,304)
  u16*   qt     = (u16*)  (ws + 22052864);     // 8192x256 bf16 (4,194,304)
  u16*   kbuf   = (u16*)  (ws + 26247168);     // 2x8x8x1152x32 (9,437,184)
  u16*   vbufT  = (u16*)  (ws + 35684352);     // 2x8x8x32x1152 (9,437,184)
  u16*   o_c    = (u16*)  (ws + 45121536);     // 8192x256 bf16
  u16*   o_t    = (u16*)  (ws + 49315840);
  u16*   wA     = (u16*)  (ws + 57704448);     // 1280x256
  u16*   wB     = (u16*)  (ws + 58359808);     // 256x256
  u16*   woc    = (u16*)  (ws + 58490880);
  u16*   wot    = (u16*)  (ws + 58621952);
  u16*   w1b    = (u16*)  (ws + 58753024);     // 1024x256
  u16*   w2b    = (u16*)  (ws + 59277312);     // 256x1024
  float* bA     = (float*)(ws + 59801600);     // 1280
  float* bB     = (float*)(ws + 59806720);     // 256
  int*   slotm  = (int*)  (ws + 59807744);     // 8192
  int*   qcnt_c = (int*)  (ws + 59840512);     // 8
  int*   qcnt_t = (int*)  (ws + 59840544);     // 8  -> end 59,840,576
  // aliases over dead regions:
  u16*   po_c   = (u16*)  (ws + 8421376);      // over qc (dead after attn)
  u16*   po_t   = (u16*)  (ws + 13139968);     // over xnc (dead after qkv)
  u16*   hmid   = (u16*)  (ws + 22052864);     // over qt+kbuf+vbuf head (16.8 MB)
  u16*   hln    = (u16*)  (ws + 45121536);     // over o_c (dead after wo)
  float* x1     = (float*)(ws + 49315840);     // over o_t.. (8,388,608)

  cvt_kernel<<<dim3(1034), 256, 0, stream>>>(cWqkv, tWqkv, cWo, tWo, W1, W2,
                                             cbqkv, tbqkv,
                                             wA, wB, woc, wot, w1b, w2b, bA, bB,
                                             labels, slotm, qcnt_c, qcnt_t, xnc, xnt);
  prep_kernel<<<dim3(2056), 256, 0, stream>>>(x, coords, labels, tgt_e, ctx_e,
                                              regs, rope, ng, nb, slotm, x0, xnc, xnt);
  gemm_qkv<<<dim3(10, 136), 256, 0, stream>>>(xnc, xnt, wA, wB, bA, bB,
                                              qc, qt, kbuf, vbufT, qcnt_c, qcnt_t);
  attn4_kernel<<<dim3(17, 8, 8), 256, 0, stream>>>(qc, qt, kbuf, vbufT, cbqkv, tbqkv,
                                                   qcnt_c, qcnt_t, o_c, o_t);
  gemm_wo<<<dim3(2, 128, 2), 256, 0, stream>>>(o_c, o_t, woc, wot, cbo, tbo,
                                               po_c, po_t, qcnt_c, qcnt_t);
  select_ln_kernel<<<dim3(2048), 256, 0, stream>>>(x0, po_c, po_t, labels, slotm, mg, mbeta, x1, hln);
  gemm_bt<4, 1, u16><<<dim3(8, 64), 256, 0, stream>>>(hln, 256, w1b, 256, b1, hmid, 1024, 8192, nullptr);
  gemm_bt<2, 2, float><<<dim3(2, 128), 256, 0, stream>>>(hmid, 1024, w2b, 1024, b2, (float*)d_out, 256, 8192, x1);
}